// Round 14
// baseline (699.060 us; speedup 1.0000x reference)
//
#include <hip/hip_runtime.h>
#include <hip/hip_bf16.h>

#define B_TOK 16384
#define IN_DIM 128
#define D_DIM 512
#define DEPTH 3
#define NEXP 8
#define FF_DIM 2048
#define EH_DIM 256
#define MAXSLOT 34816
#define MAXT256 136
#define NHBLK 64

typedef __attribute__((ext_vector_type(8))) __bf16 bf16x8;
typedef __attribute__((ext_vector_type(4))) float f32x4;
typedef __attribute__((ext_vector_type(4))) unsigned short u16x4;
typedef __attribute__((ext_vector_type(8))) unsigned short u16x8;

__device__ __forceinline__ unsigned short f2bf(float f){
    unsigned int u = __float_as_uint(f);
    u += 0x7fffu + ((u >> 16) & 1u);
    return (unsigned short)(u >> 16);
}
__device__ __forceinline__ float bf2f(unsigned short u){
    return __uint_as_float(((unsigned int)u) << 16);
}
__device__ __forceinline__ float geluf(float x){
    float x2 = x * x;
    float y  = x * (0.79788456080287f + 0.03567740814183f * x2);
    y = fminf(fmaxf(y, -15.0f), 15.0f);
    float e = __expf(2.0f * y);
    float th = 1.0f - 2.0f / (e + 1.0f);
    return 0.5f * x * (1.0f + th);
}
__device__ __forceinline__ void gload_lds16(const void* g, void* l){
    __builtin_amdgcn_global_load_lds((const __attribute__((address_space(1))) unsigned int*)g,
                                     (__attribute__((address_space(3))) unsigned int*)l,
                                     16, 0, 0);
}
__device__ __forceinline__ int xcd_swizzle(int orig, int nwg){
    const int q = nwg >> 3, r = nwg & 7;
    const int xcd = orig & 7;
    const int idx = orig >> 3;
    return (xcd < r ? xcd*(q+1) : r*(q+1) + (xcd-r)*q) + idx;
}

// ---------------- zero scratch control state ------------------------------
__global__ void zero_kernel(int* a, int na, int* b, int nb){
    const int i = blockIdx.x * blockDim.x + threadIdx.x;
    if (i < na) a[i] = 0;
    if (i < nb) b[i] = 0;
}

// ---------------- fp32 -> bf16 convert ------------------------------------
struct ConvSeg { const float* src; unsigned short* dst; int n4; };
struct ConvArgs { ConvSeg seg[2]; };

__global__ void convert_kernel(ConvArgs a){
    const int stride = gridDim.x * blockDim.x;
    const int tid = blockIdx.x * blockDim.x + threadIdx.x;
    for (int s = 0; s < 2; ++s){
        const f32x4* src = (const f32x4*)a.seg[s].src;
        u16x4* dst = (u16x4*)a.seg[s].dst;
        const int n4 = a.seg[s].n4;
        for (int i = tid; i < n4; i += stride){
            f32x4 v = src[i];
            u16x4 o;
            o[0] = f2bf(v[0]); o[1] = f2bf(v[1]); o[2] = f2bf(v[2]); o[3] = f2bf(v[3]);
            dst[i] = o;
        }
    }
}

// ------- weight transpose-convert with optional LN-gamma fold -------------
// axis 0: none; 1: scale by dst col k (scl[k0+tx]); 2: scale by dst row n.
struct TSeg { const float* src; unsigned short* dst; int K; int N; int tileStart;
              const float* scl; int axis; };
struct TArgs { TSeg seg[26]; };

__global__ void transpose_kernel(TArgs a){
    __shared__ float t[32][33];
    const int tile = blockIdx.x;
    int s = 0;
    #pragma unroll 1
    while (s < 25 && tile >= a.seg[s+1].tileStart) ++s;
    const TSeg sg = a.seg[s];
    const int local = tile - sg.tileStart;
    const int tilesN = sg.N >> 5;
    const int k0 = (local / tilesN) << 5;
    const int n0 = (local % tilesN) << 5;
    const int tx = threadIdx.x & 31;
    const int ty = threadIdx.x >> 5;
    #pragma unroll
    for (int j = 0; j < 4; ++j)
        t[ty + j*8][tx] = sg.src[(size_t)(k0 + ty + j*8) * sg.N + n0 + tx];
    __syncthreads();
    const float sk = (sg.axis == 1) ? sg.scl[k0 + tx] : 1.0f;
    #pragma unroll
    for (int j = 0; j < 4; ++j){
        const int n = ty + j*8;
        float v = t[tx][n] * sk;
        if (sg.axis == 2) v *= sg.scl[n0 + n];
        sg.dst[(size_t)(n0 + n) * sg.K + k0 + tx] = f2bf(v);
    }
}

// ------- t2[l,j] = sum_k Wv[j,k]*ln1_b[l,k] + bv[l,j]  (wave per output) --
__global__ void t2_kernel(const float* __restrict__ inproj_w, const float* __restrict__ inproj_b,
                          const float* __restrict__ ln1_b, float* __restrict__ t2){
    const int wave = threadIdx.x >> 6, lane = threadIdx.x & 63;
    const int o = blockIdx.x * 4 + wave;         // 0..1535
    const int l = o >> 9, j = o & 511;
    const float* Wv = inproj_w + (size_t)l*3*D_DIM*D_DIM + (size_t)2*D_DIM*D_DIM + (size_t)j*D_DIM;
    const float* b1 = ln1_b + l*D_DIM;
    float s = 0.f;
    #pragma unroll
    for (int q = 0; q < 8; ++q) s += Wv[lane + q*64] * b1[lane + q*64];
    #pragma unroll
    for (int off = 32; off > 0; off >>= 1) s += __shfl_xor(s, off);
    if (lane == 0) t2[o] = s + inproj_b[l*3*D_DIM + 2*D_DIM + j];
}

// ------- cca[l,n] = sum_j Wo[n,j]*t2[l,j] + bo[l,n]  (wave per output) ----
__global__ void cca_kernel(const float* __restrict__ outproj_w, const float* __restrict__ outproj_b,
                           const float* __restrict__ t2, float* __restrict__ cca){
    const int wave = threadIdx.x >> 6, lane = threadIdx.x & 63;
    const int o = blockIdx.x * 4 + wave;
    const int l = o >> 9, n = o & 511;
    const float* Wo = outproj_w + ((size_t)l*D_DIM + n)*D_DIM;
    const float* tt = t2 + l*D_DIM;
    float s = 0.f;
    #pragma unroll
    for (int q = 0; q < 8; ++q) s += Wo[lane + q*64] * tt[lane + q*64];
    #pragma unroll
    for (int off = 32; off > 0; off >>= 1) s += __shfl_xor(s, off);
    if (lane == 0) cca[o] = s + outproj_b[o];
}

// ------- row sums of scaled bf16 weights: c1a (wfold), c1f (w1t) ----------
__global__ void rowsum_kernel(const unsigned short* __restrict__ wfold,
                              const unsigned short* __restrict__ w1t,
                              float* __restrict__ c1a, float* __restrict__ c1f){
    const int wave = threadIdx.x >> 6, lane = threadIdx.x & 63;
    const int o = blockIdx.x * 4 + wave;          // 0..7679
    const unsigned short* src;
    float* dst;
    if (o < DEPTH*D_DIM){ src = wfold + (size_t)o*D_DIM; dst = c1a + o; }
    else { src = w1t + (size_t)(o - DEPTH*D_DIM)*D_DIM; dst = c1f + (o - DEPTH*D_DIM); }
    u16x8 v = *(const u16x8*)(src + lane*8);
    float s = 0.f;
    #pragma unroll
    for (int q = 0; q < 8; ++q) s += bf2f(v[q]);
    #pragma unroll
    for (int off = 32; off > 0; off >>= 1) s += __shfl_xor(s, off);
    if (lane == 0) *dst = s;
}

// ------- ccf[l,n] = sum_k ln2_b[l,k]*ffn_w1[l,k,n] + ffn_b1[l,n] ----------
__global__ void ccf_kernel(const float* __restrict__ ffn_w1, const float* __restrict__ ffn_b1,
                           const float* __restrict__ ln2_b, float* __restrict__ ccf){
    __shared__ float lb[512];
    const int l = blockIdx.x >> 3;
    const int n0 = (blockIdx.x & 7) * 256;
    const int t = threadIdx.x;
    lb[t] = ln2_b[l*D_DIM + t];
    lb[t + 256] = ln2_b[l*D_DIM + t + 256];
    __syncthreads();
    const float* W = ffn_w1 + (size_t)l*D_DIM*FF_DIM;
    float acc = 0.f;
    #pragma unroll 1
    for (int k = 0; k < D_DIM; ++k) acc += lb[k] * W[(size_t)k*FF_DIM + n0 + t];
    ccf[l*FF_DIM + n0 + t] = acc + ffn_b1[l*FF_DIM + n0 + t];
}

// ---------------- small GEMM: 128x128, dbuf, bf16 out, layer-batched ------
__global__ void __launch_bounds__(256, 2)
gemm_bt(const unsigned short* __restrict__ A0, const unsigned short* __restrict__ Bt0,
        const float* __restrict__ bias, unsigned short* __restrict__ out0,
        int NB, int N, int K, int nper, size_t lsa, size_t lsb, size_t lsc)
{
    __shared__ unsigned short sh[32768];
    const int nwg = gridDim.x;
    int wg  = xcd_swizzle(blockIdx.x, nwg);
    const int layer = wg / nper;
    wg -= layer * nper;
    const unsigned short* A  = A0  + (size_t)layer * lsa;
    const unsigned short* Bt = Bt0 + (size_t)layer * lsb;
    unsigned short* out = out0 + (size_t)layer * lsc;
    const int bn  = wg % NB;
    const int bm  = wg / NB;

    const int tid  = threadIdx.x;
    const int lane = tid & 63;
    const int wave = tid >> 6;
    const int wm = (wave >> 1) << 6;
    const int wn = (wave & 1) << 6;

    f32x4 acc[4][4] = {};

    const unsigned short* Abase = A + (size_t)bm * 128 * K;
    const unsigned short* Bbase = Bt + (size_t)bn * 128 * K;
    const int soff = tid * 16;

    auto STAGE = [&](int b, int kt){
        char* Ab = (char*)(sh + b*16384);
        char* Bb = (char*)(sh + b*16384 + 8192);
        #pragma unroll
        for (int s = 0; s < 4; ++s){
            const int off = s*4096 + soff;
            const int row = off >> 7, colb = off & 127;
            gload_lds16((const char*)(Abase + (size_t)row*K + kt) + colb, Ab + off);
        }
        #pragma unroll
        for (int s = 0; s < 4; ++s){
            const int off = s*4096 + soff;
            const int row = off >> 7, colb = off & 127;
            gload_lds16((const char*)(Bbase + (size_t)row*K + kt) + colb, Bb + off);
        }
    };
    auto COMPUTE = [&](int b){
        const unsigned short* Ab = sh + b*16384;
        const unsigned short* Bb = sh + b*16384 + 8192;
        #pragma unroll
        for (int ks = 0; ks < 2; ++ks){
            const int k0 = ks*32 + ((lane>>4)<<3);
            bf16x8 af[4], bfr[4];
            #pragma unroll
            for (int i=0;i<4;i++) af[i]  = *(const bf16x8*)&Ab[(wm + i*16 + (lane&15))*64 + k0];
            #pragma unroll
            for (int j=0;j<4;j++) bfr[j] = *(const bf16x8*)&Bb[(wn + j*16 + (lane&15))*64 + k0];
            #pragma unroll
            for (int i=0;i<4;i++)
                #pragma unroll
                for (int j=0;j<4;j++)
                    acc[i][j] = __builtin_amdgcn_mfma_f32_16x16x32_bf16(af[i], bfr[j], acc[i][j], 0, 0, 0);
        }
    };

    STAGE(0, 0);
    __syncthreads();
    const int nk = K >> 6;
    int cur = 0;
    for (int i = 0; i < nk; ++i){
        if (i + 1 < nk) STAGE(cur ^ 1, (i + 1) << 6);
        COMPUTE(cur);
        __syncthreads();
        cur ^= 1;
    }

    const int r0 = ((lane>>4)<<2);
    const int cc = lane & 15;
    unsigned short* Ct = sh;
    float bcol[4];
    #pragma unroll
    for (int j=0;j<4;j++) bcol[j] = bias[bn*128 + wn + j*16 + cc];
    #pragma unroll
    for (int i=0;i<4;i++)
        #pragma unroll
        for (int r=0;r<4;r++){
            const int rl = wm + i*16 + r0 + r;
            #pragma unroll
            for (int j=0;j<4;j++)
                Ct[rl*128 + wn + j*16 + cc] = f2bf(acc[i][j][r] + bcol[j]);
        }
    __syncthreads();
    const int orow = tid >> 4;
    const int ocol = (tid & 15) * 8;
    #pragma unroll
    for (int p = 0; p < 8; ++p){
        const int row = p*16 + orow;
        *(u16x8*)(&out[(size_t)(bm*128 + row)*N + bn*128 + ocol]) = *(u16x8*)&Ct[row*128 + ocol];
    }
}

// ===== 256x256 GEMM 2-phase dbuf (ffn1): LN-fused epilogue ================
// out = gelu(r*acc - m*r*c1[col] + cc[col])
__global__ void __launch_bounds__(512, 2)
gemm256sq(const unsigned short* __restrict__ A, const unsigned short* __restrict__ Bt,
          const float* __restrict__ cc, const float* __restrict__ c1,
          const float2* __restrict__ mr, unsigned short* __restrict__ out,
          int NB, int N, int K)
{
    __shared__ __align__(16) char sh[131072];
    const int nwg = gridDim.x;
    const int wg  = xcd_swizzle(blockIdx.x, nwg);
    const int bn  = wg % NB;
    const int bm  = wg / NB;
    const int m0  = bm * 256;
    const int n0  = bn * 256;

    const int tid = threadIdx.x, lane = tid & 63, wave = tid >> 6;
    const int wr = wave >> 2;
    const int wc = wave & 3;

    const int srow = wave*16 + (lane >> 3);
    const int scol = ((lane & 7) ^ (lane >> 3)) * 8;
    const unsigned short* aptr[2][2];
    const unsigned short* bptr[2][2];
    #pragma unroll
    for (int u = 0; u < 2; ++u)
        #pragma unroll
        for (int l = 0; l < 2; ++l){
            aptr[u][l] = A  + (size_t)(m0 + u*128 + srow + l*8) * K + scol;
            bptr[u][l] = Bt + (size_t)(n0 + u*128 + srow + l*8) * K + scol;
        }
    const int sdst = wave*2048 + lane*16;

    int ch[2];
    #pragma unroll
    for (int ks = 0; ks < 2; ++ks)
        ch[ks] = ((((ks<<2) + (lane>>4)) ^ (lane & 7)) << 4);
    const int arow = wr*128 + (lane & 15);
    const int brow = wc*64  + (lane & 15);

    f32x4 acc[8][4] = {};

    auto STAGE = [&](int buf, int kt){
        #pragma unroll
        for (int u = 0; u < 2; ++u)
            #pragma unroll
            for (int l = 0; l < 2; ++l)
                gload_lds16(aptr[u][l] + kt, sh + buf*32768 + u*16384 + l*1024 + sdst);
        #pragma unroll
        for (int u = 0; u < 2; ++u)
            #pragma unroll
            for (int l = 0; l < 2; ++l)
                gload_lds16(bptr[u][l] + kt, sh + 65536 + buf*32768 + u*16384 + l*1024 + sdst);
    };
    auto COMPUTE = [&](int buf){
        bf16x8 bfr[4][2];
        #pragma unroll
        for (int nf = 0; nf < 4; ++nf)
            #pragma unroll
            for (int ks = 0; ks < 2; ++ks)
                bfr[nf][ks] = *(const bf16x8*)(sh + 65536 + buf*32768 + (brow + nf*16)*128 + ch[ks]);
        #pragma unroll
        for (int mf = 0; mf < 8; ++mf){
            bf16x8 af[2];
            #pragma unroll
            for (int ks = 0; ks < 2; ++ks)
                af[ks] = *(const bf16x8*)(sh + buf*32768 + (arow + mf*16)*128 + ch[ks]);
            #pragma unroll
            for (int nf = 0; nf < 4; ++nf)
                #pragma unroll
                for (int ks = 0; ks < 2; ++ks)
                    acc[mf][nf] = __builtin_amdgcn_mfma_f32_16x16x32_bf16(af[ks], bfr[nf][ks], acc[mf][nf], 0,0,0);
        }
    };

    STAGE(0, 0);
    __syncthreads();
    const int nk = K >> 6;
    int cur = 0;
    for (int i = 0; i < nk; ++i){
        if (i + 1 < nk) STAGE(cur ^ 1, (i + 1) << 6);
        COMPUTE(cur);
        __syncthreads();
        cur ^= 1;
    }

    unsigned short* Ct = (unsigned short*)sh;
    const int r4 = (lane >> 4) * 4;
    const int cc15 = lane & 15;
    float c1v[4], ccv[4];
    #pragma unroll
    for (int nf = 0; nf < 4; ++nf){
        const int col = n0 + wc*64 + nf*16 + cc15;
        c1v[nf] = c1[col];
        ccv[nf] = cc[col];
    }
    #pragma unroll
    for (int mf = 0; mf < 8; ++mf)
        #pragma unroll
        for (int r = 0; r < 4; ++r){
            const int row = wr*128 + mf*16 + r4 + r;
            const float2 m = mr[m0 + row];
            #pragma unroll
            for (int nf = 0; nf < 4; ++nf){
                const int col = wc*64 + nf*16 + cc15;
                Ct[row*256 + col] = f2bf(geluf(m.x*acc[mf][nf][r] - m.y*c1v[nf] + ccv[nf]));
            }
        }
    __syncthreads();
    #pragma unroll
    for (int p = 0; p < 16; ++p){
        const int uidx = p*512 + tid;
        const int row = uidx >> 5;
        const int cu  = uidx & 31;
        *(u16x8*)(out + (size_t)(m0 + row)*N + n0 + cu*8) = *(const u16x8*)(Ct + row*256 + cu*8);
    }
}

// =================== 256x128 2-phase GEMM =================================
// EPI: 0 gelu+bias (MoE e1), 1 bias+resid (ffn2), 2 gated (MoE e2),
//      3 LN-fused + resid (attn): resid + r*acc - m*r*c1[col] + biasG[col]
#define G_GELU_BF16 0
#define G_BF16_RESID 1
#define G_GATED_BF16 2
#define G_LNRESID 3

template<int EPI, int MOE, int INDIRECT>
__global__ void __launch_bounds__(512, 2)
gemm256(const unsigned short* __restrict__ A, const unsigned short* __restrict__ BtG,
        const float* __restrict__ biasG, const unsigned short* __restrict__ resid,
        const int* __restrict__ tok, const int* __restrict__ offs,
        int wstride, int bstride, const float* __restrict__ gslot,
        const float2* __restrict__ mr, const float* __restrict__ c1,
        unsigned short* __restrict__ out, int NB, int N, int K)
{
    __shared__ __align__(16) char sh[147456];
    const int nwg = gridDim.x;
    const int wg  = xcd_swizzle(blockIdx.x, nwg);
    const int bn  = wg % NB;
    const int bm  = wg / NB;
    const int m0  = bm * 256;

    const unsigned short* Bt = BtG;
    const float* bias = biasG;
    if (MOE){
        if (m0 >= offs[8]) return;
        int e = 0;
        #pragma unroll 1
        while (offs[e+1] <= m0) ++e;
        Bt   += (size_t)e * wstride;
        bias += (size_t)e * bstride;
    }

    const int tid = threadIdx.x, lane = tid & 63, wave = tid >> 6;
    const int wm = (wave >> 1) * 64;
    const int wn = (wave & 1) * 64;

    const int srow = wave*16 + (lane >> 3);
    const int scol = ((lane & 7) ^ (lane >> 3)) * 8;
    const unsigned short* aptr[2][2];
    #pragma unroll
    for (int u = 0; u < 2; ++u)
        #pragma unroll
        for (int l = 0; l < 2; ++l){
            const int r = u*128 + srow + l*8;
            const int gr = INDIRECT ? tok[m0 + r] : (m0 + r);
            aptr[u][l] = A + (size_t)gr * K + scol;
        }
    const unsigned short* bptr[2];
    #pragma unroll
    for (int l = 0; l < 2; ++l)
        bptr[l] = Bt + (size_t)(bn*128 + srow + l*8) * K + scol;
    const int sdst = wave*2048 + lane*16;

    int aoff[2], boff[2];
    #pragma unroll
    for (int ks = 0; ks < 2; ++ks){
        const int ch = (((ks<<2) + (lane>>4)) ^ (lane & 7)) << 4;
        aoff[ks] = (wm + (lane & 15))*128 + ch;
        boff[ks] = (wn + (lane & 15))*128 + ch;
    }

    f32x4 acc[4][4] = {};

    auto STAGE = [&](int buf, int kt){
        #pragma unroll
        for (int u = 0; u < 2; ++u)
            #pragma unroll
            for (int l = 0; l < 2; ++l)
                gload_lds16(aptr[u][l] + kt, sh + buf*32768 + u*16384 + l*1024 + sdst);
        #pragma unroll
        for (int l = 0; l < 2; ++l)
            gload_lds16(bptr[l] + kt, sh + 98304 + buf*16384 + l*1024 + sdst);
    };
    auto COMPUTE = [&](int buf){
        bf16x8 bfr[4][2];
        #pragma unroll
        for (int nf = 0; nf < 4; ++nf)
            #pragma unroll
            for (int ks = 0; ks < 2; ++ks)
                bfr[nf][ks] = *(const bf16x8*)(sh + 98304 + buf*16384 + nf*2048 + boff[ks]);
        #pragma unroll
        for (int mf = 0; mf < 4; ++mf){
            bf16x8 af[2];
            #pragma unroll
            for (int ks = 0; ks < 2; ++ks)
                af[ks] = *(const bf16x8*)(sh + buf*32768 + mf*2048 + aoff[ks]);
            #pragma unroll
            for (int nf = 0; nf < 4; ++nf)
                #pragma unroll
                for (int ks = 0; ks < 2; ++ks)
                    acc[mf][nf] = __builtin_amdgcn_mfma_f32_16x16x32_bf16(af[ks], bfr[nf][ks], acc[mf][nf], 0,0,0);
        }
    };

    STAGE(0, 0);
    __syncthreads();
    const int nk = K >> 6;
    int cur = 0;
    for (int i = 0; i < nk; ++i){
        if (i + 1 < nk) STAGE(cur ^ 1, (i + 1) << 6);
        COMPUTE(cur);
        __syncthreads();
        cur ^= 1;
    }

    const int r4 = (lane >> 4) * 4;
    const int cc15 = lane & 15;
    if (EPI == G_BF16_RESID || EPI == G_LNRESID){
        float* ctf = (float*)sh;
        float bcol[4], c1v[4];
        #pragma unroll
        for (int nf = 0; nf < 4; ++nf){
            bcol[nf] = bias[bn*128 + wn + nf*16 + cc15];
            if (EPI == G_LNRESID) c1v[nf] = c1[bn*128 + wn + nf*16 + cc15];
        }
        #pragma unroll
        for (int mf = 0; mf < 4; ++mf)
            #pragma unroll
            for (int r = 0; r < 4; ++r){
                const int row = wm + mf*16 + r4 + r;
                float2 m = make_float2(1.f, 0.f);
                if (EPI == G_LNRESID) m = mr[m0 + row];
                #pragma unroll
                for (int nf = 0; nf < 4; ++nf){
                    float v;
                    if (EPI == G_LNRESID) v = m.x*acc[mf][nf][r] - m.y*c1v[nf] + bcol[nf];
                    else                  v = acc[mf][nf][r] + bcol[nf];
                    ctf[row*128 + wn + nf*16 + cc15] = v;
                }
            }
        __syncthreads();
        #pragma unroll
        for (int p = 0; p < 8; ++p){
            const int uidx = p*512 + tid;
            const int row = uidx >> 4;
            const int cu  = uidx & 15;
            const size_t gidx = (size_t)(m0 + row)*N + bn*128 + cu*8;
            u16x8 hv = *(const u16x8*)(resid + gidx);
            u16x8 o;
            #pragma unroll
            for (int j = 0; j < 8; ++j)
                o[j] = f2bf(bf2f(hv[j]) + ctf[row*128 + cu*8 + j]);
            *(u16x8*)(out + gidx) = o;
        }
    } else {
        unsigned short* ct = (unsigned short*)sh;
        #pragma unroll
        for (int nf = 0; nf < 4; ++nf){
            const float bv = bias[bn*128 + wn + nf*16 + cc15];
            #pragma unroll
            for (int mf = 0; mf < 4; ++mf)
                #pragma unroll
                for (int r = 0; r < 4; ++r){
                    const int row = wm + mf*16 + r4 + r;
                    float v = acc[mf][nf][r] + bv;
                    if (EPI == G_GELU_BF16) v = geluf(v);
                    else                    v *= gslot[m0 + row];
                    ct[row*128 + wn + nf*16 + cc15] = f2bf(v);
                }
        }
        __syncthreads();
        #pragma unroll
        for (int p = 0; p < 8; ++p){
            const int uidx = p*512 + tid;
            const int row = uidx >> 4;
            const int cu  = uidx & 15;
            *(u16x8*)(out + (size_t)(m0 + row)*N + bn*128 + cu*8) =
                *(const u16x8*)(ct + row*128 + cu*8);
        }
    }
}

// ---------------- LN stats only: mr[row] = {1/sigma, mean/sigma} ----------
__global__ void stats_kernel(const unsigned short* __restrict__ x, float2* __restrict__ mr)
{
    const int lane = threadIdx.x & 63;
    const int wave = threadIdx.x >> 6;
    const int row  = blockIdx.x * 4 + wave;
    u16x8 hv = *(const u16x8*)(x + (size_t)row * D_DIM + lane*8);
    float s = 0.f, s2 = 0.f;
    #pragma unroll
    for (int j = 0; j < 8; ++j){ const float v = bf2f(hv[j]); s += v; s2 += v*v; }
    #pragma unroll
    for (int o = 32; o > 0; o >>= 1){ s += __shfl_xor(s, o); s2 += __shfl_xor(s2, o); }
    if (lane == 0){
        const float mean = s * (1.0f/512.0f);
        const float var  = s2 * (1.0f/512.0f) - mean*mean;
        const float inv  = 1.0f / sqrtf(var + 1e-5f);
        mr[row] = make_float2(inv, mean*inv);
    }
}

// ------- Router: softmax+eps-mix+top2 (bf16 z in, no global atomics) ------
__global__ void router_kernel(const unsigned short* __restrict__ z, const float* __restrict__ rw,
                              const float* __restrict__ rb,
                              int2* __restrict__ idx2, float2* __restrict__ wts2,
                              float* __restrict__ bsums)
{
    __shared__ float ps[4][8];
    const int lane = threadIdx.x & 63;
    const int wave = threadIdx.x >> 6;
    const int row  = blockIdx.x * 4 + wave;
    u16x8 hv = *(const u16x8*)(z + (size_t)row * D_DIM + lane*8);
    float acc[8] = {0,0,0,0,0,0,0,0};
    #pragma unroll
    for (int j = 0; j < 8; ++j){
        const float zv = bf2f(hv[j]);
        const float* wr = rw + (size_t)(lane*8 + j) * 8;
        f32x4 w0 = *(const f32x4*)wr;
        f32x4 w1 = *(const f32x4*)(wr + 4);
        acc[0] += zv*w0[0]; acc[1] += zv*w0[1]; acc[2] += zv*w0[2]; acc[3] += zv*w0[3];
        acc[4] += zv*w1[0]; acc[5] += zv*w1[1]; acc[6] += zv*w1[2]; acc[7] += zv*w1[3];
    }
    #pragma unroll
    for (int o = 32; o > 0; o >>= 1){
        #pragma unroll
        for (int e = 0; e < 8; ++e) acc[e] += __shfl_xor(acc[e], o);
    }
    if (lane == 0){
        float p[8]; float mx = -1e30f;
        #pragma unroll
        for (int e=0;e<8;e++){ p[e] = acc[e] + rb[e]; mx = fmaxf(mx, p[e]); }
        float se = 0.f;
        #pragma unroll
        for (int e=0;e<8;e++){ p[e] = expf(p[e]-mx); se += p[e]; }
        const float sc = 0.9f / se;
        #pragma unroll
        for (int e=0;e<8;e++) p[e] = p[e]*sc + 0.0125f;
        int i1 = 0;
        #pragma unroll
        for (int e=1;e<8;e++) if (p[e] > p[i1]) i1 = e;
        int i2 = (i1 == 0) ? 1 : 0;
        for (int e=i2+1;e<8;e++) if (e != i1 && p[e] > p[i2]) i2 = e;
        idx2[row] = make_int2(i1, i2);
        wts2[row] = make_float2(p[i1], p[i2]);
        #pragma unroll
        for (int e=0;e<8;e++) ps[wave][e] = p[e];
    }
    __syncthreads();
    if (threadIdx.x < 8){
        bsums[blockIdx.x*8 + threadIdx.x] =
            ps[0][threadIdx.x] + ps[1][threadIdx.x] + ps[2][threadIdx.x] + ps[3][threadIdx.x];
    }
}

// ------- histogram / scan / assign (block-local, no global atomics) -------
__global__ void hist_kernel(const int2* __restrict__ idx2, int* __restrict__ blockHist){
    __shared__ int hc[8];
    if (threadIdx.x < 8) hc[threadIdx.x] = 0;
    __syncthreads();
    const int t = blockIdx.x * 256 + threadIdx.x;
    const int2 ii = idx2[t];
    atomicAdd(&hc[ii.x], 1);
    atomicAdd(&hc[ii.y], 1);
    __syncthreads();
    if (threadIdx.x < 8) blockHist[blockIdx.x*8 + threadIdx.x] = hc[threadIdx.x];
}

__global__ void scan_kernel(const int* __restrict__ blockHist, int* __restrict__ offs,
                            int* __restrict__ baseArr){
    __shared__ int hist[NHBLK*8];
    __shared__ int cnt[8];
    __shared__ int start[8];
    const int t = threadIdx.x;
    hist[t] = blockHist[t];
    __syncthreads();
    if (t < 8){
        int c = 0;
        #pragma unroll 1
        for (int b = 0; b < NHBLK; ++b) c += hist[b*8 + t];
        cnt[t] = c;
    }
    __syncthreads();
    if (t == 0){
        int o = 0; offs[0] = 0;
        for (int e = 0; e < 8; ++e){ start[e] = o; o += (cnt[e]+255)&~255; offs[e+1] = o; }
    }
    __syncthreads();
    if (t < 8){
        int cur = start[t];
        #pragma unroll 1
        for (int b = 0; b < NHBLK; ++b){ baseArr[b*8 + t] = cur; cur += hist[b*8 + t]; }
    }
}

__global__ void assign_kernel(const int2* __restrict__ idx2, const float2* __restrict__ wts2,
                              const int* __restrict__ baseArr, int2* __restrict__ slot_map,
                              float* __restrict__ gslot, int* __restrict__ tok)
{
    __shared__ int cur[8];
    if (threadIdx.x < 8) cur[threadIdx.x] = 0;
    __syncthreads();
    const int t = blockIdx.x * 256 + threadIdx.x;
    const int2 ii = idx2[t];
    const float2 ww = wts2[t];
    const int r1 = atomicAdd(&cur[ii.x], 1);
    const int r2 = atomicAdd(&cur[ii.y], 1);
    const int s1 = baseArr[blockIdx.x*8 + ii.x] + r1;
    const int s2 = baseArr[blockIdx.x*8 + ii.y] + r2;
    slot_map[t] = make_int2(s1, s2);
    gslot[s1] = ww.x; gslot[s2] = ww.y;
    tok[s1] = t; tok[s2] = t;
}

// ---------------- aux loss ------------------------------------------------
__global__ void aux_kernel(const float* __restrict__ bsums, float* __restrict__ out_aux)
{
    __shared__ float part[256];
    const int t = threadIdx.x;
    const int e = t & 7, chunk = t >> 3;
    float s = 0.f;
    for (int blk = chunk*128; blk < chunk*128 + 128; ++blk) s += bsums[blk*8 + e];
    part[t] = s;
    __syncthreads();
    if (t < 8){
        float tot = 0.f;
        for (int c = 0; c < 32; ++c) tot += part[c*8 + t];
        part[t] = tot;
    }
    __syncthreads();
    if (t == 0){
        float aux = 0.f;
        for (int e2 = 0; e2 < 8; ++e2){
            float load = part[e2] * (1.0f/16384.0f);
            aux += load * logf(load * 8.0f + 1e-9f);
        }
        out_aux[0] = aux / 2.0794415416798357f;
    }
}

// -------- head: z = h + eo[s1] + eo[s2]; LN; dot --------------------------
__global__ void head_kernel(const unsigned short* __restrict__ h, const unsigned short* __restrict__ eog,
                            const int2* __restrict__ slot_map,
                            const float* __restrict__ w, const float* __restrict__ b,
                            const float* __restrict__ hw, const float* __restrict__ hb,
                            float* __restrict__ out)
{
    const int lane = threadIdx.x & 63;
    const int wave = threadIdx.x >> 6;
    const int row  = blockIdx.x * 4 + wave;
    const int2 sm = slot_map[row];
    u16x8 hv = *(const u16x8*)(h + (size_t)row * D_DIM + lane*8);
    u16x8 e1 = *(const u16x8*)(eog + (size_t)sm.x * D_DIM + lane*8);
    u16x8 e2 = *(const u16x8*)(eog + (size_t)sm.y * D_DIM + lane*8);
    float v[8];
    #pragma unroll
    for (int j=0;j<8;j++) v[j] = bf2f(hv[j]) + bf2f(e1[j]) + bf2f(e2[j]);
    float s = 0.f, s2 = 0.f;
    #pragma unroll
    for (int j=0;j<8;j++){ s += v[j]; s2 += v[j]*v[j]; }
    #pragma unroll
    for (int o = 32; o > 0; o >>= 1){ s += __shfl_xor(s, o); s2 += __shfl_xor(s2, o); }
    const float mean = s * (1.0f/512.0f);
    const float var  = s2 * (1.0f/512.0f) - mean*mean;
    const float inv  = 1.0f / sqrtf(var + 1e-5f);
    const int k = lane*8;
    float dot = 0.f;
    #pragma unroll
    for (int j=0;j<8;j++) dot += ((v[j]-mean)*inv*w[k+j] + b[k+j]) * hw[k+j];
    #pragma unroll
    for (int o = 32; o > 0; o >>= 1) dot += __shfl_xor(dot, o);
    if (lane == 0) out[row] = dot + hb[0];
}

// ===========================================================================
extern "C" void kernel_launch(void* const* d_in, const int* in_sizes, int n_in,
                              void* d_out, int out_size, void* d_ws, size_t ws_size,
                              hipStream_t stream)
{
    (void)in_sizes; (void)n_in; (void)out_size; (void)ws_size;
    const float* x         = (const float*)d_in[0];
    const float* embed_w   = (const float*)d_in[1];
    const float* embed_b   = (const float*)d_in[2];
    const float* ln1_w     = (const float*)d_in[3];
    const float* ln1_b     = (const float*)d_in[4];
    const float* inproj_w  = (const float*)d_in[5];
    const float* inproj_b  = (const float*)d_in[6];
    const float* outproj_w = (const float*)d_in[7];
    const float* outproj_b = (const float*)d_in[8];
    const float* ln2_w     = (const float*)d_in[9];
    const float* ln2_b     = (const float*)d_in[10];
    const float* ffn_w1    = (const float*)d_in[11];
    const float* ffn_b1    = (const float*)d_in[12];
    const float* ffn_w2    = (const float*)d_in[13];
    const float* ffn_b2    = (const float*)d_in[14];
    const float* router_w  = (const float*)d_in[15];
    const float* router_b  = (const float*)d_in[16];
    const float* exp_w1    = (const float*)d_in[17];
    const float* exp_b1    = (const float*)d_in[18];
    const float* exp_w2    = (const float*)d_in[19];
    const float* exp_b2    = (const float*)d_in[20];
    const float* head_ln_w = (const float*)d_in[21];
    const float* head_ln_b = (const float*)d_in[22];
    const float* head_w    = (const float*)d_in[23];
    const float* head_b    = (const float*)d_in[24];

    char* ws = (char*)d_ws;
    unsigned short* xbf   = (unsigned short*)(ws + 0);
    unsigned short* ebf   = (unsigned short*)(ws + 4194304);
    unsigned short* wobf  = (unsigned short*)(ws + 4325376);
    unsigned short* wvtbf = (unsigned short*)(ws + 5898240);
    unsigned short* wfold = (unsigned short*)(ws + 7471104);
    unsigned short* w1t   = (unsigned short*)(ws + 9043968);
    unsigned short* w2t   = (unsigned short*)(ws + 15335424);
    unsigned short* e1t   = (unsigned short*)(ws + 21626880);
    unsigned short* e2t   = (unsigned short*)(ws + 23724032);
    unsigned short* h     = (unsigned short*)(ws + 25821184);
    unsigned short* ubf   = (unsigned short*)(ws + 59375616);
    unsigned short* hmidg = ubf;
    unsigned short* eog   = (unsigned short*)(ws + 77201408);
    char* MISC = ws + 126484480;
    int*    offs     = (int*)(MISC + 0);
    float*  zbias    = (float*)(MISC + 256);
    int2*   idx2     = (int2*)(MISC + 8448);
    float2* wts2     = (float2*)(MISC + 139520);
    int2*   slot_map = (int2*)(MISC + 270592);
    float*  gslot    = (float*)(MISC + 401664);
    int*    tok      = (int*)(MISC + 544768);
    float*  bsums    = (float*)(MISC + 684032);
    int*    blockHist= (int*)(MISC + 815104);
    int*    baseArr  = (int*)(MISC + 817152);
    float2* mr       = (float2*)(MISC + 860160);   // 131072
    float*  t2buf    = (float*)(MISC + 991232);    //   6144
    float*  cca      = (float*)(MISC + 997376);    //   6144
    float*  c1a      = (float*)(MISC + 1003520);   //   6144
    float*  c1f      = (float*)(MISC + 1009664);   //  24576
    float*  ccf      = (float*)(MISC + 1034240);   //  24576
    float* out = (float*)d_out;

    zero_kernel<<<(MAXSLOT + 255)/256, 256, 0, stream>>>((int*)zbias, 512, tok, MAXSLOT);

    ConvArgs ca;
    ca.seg[0] = { x, xbf, B_TOK*IN_DIM/4 };
    ca.seg[1] = { outproj_w, wobf, DEPTH*D_DIM*D_DIM/4 };
    convert_kernel<<<1024, 256, 0, stream>>>(ca);

    TArgs ta;
    int tcur = 0, ti = 0;
    ta.seg[ti] = { embed_w, ebf, IN_DIM, D_DIM, tcur, nullptr, 0 };
    tcur += (IN_DIM/32)*(D_DIM/32); ++ti;
    for (int l = 0; l < DEPTH; ++l){   // w1t scaled by ln2_w over k (axis 1)
        ta.seg[ti] = { ffn_w1 + (size_t)l*D_DIM*FF_DIM, w1t + (size_t)l*FF_DIM*D_DIM,
                       D_DIM, FF_DIM, tcur, ln2_w + l*D_DIM, 1 };
        tcur += (D_DIM/32)*(FF_DIM/32); ++ti;
    }
    for (int l = 0; l < DEPTH; ++l){
        ta.seg[ti] = { ffn_w2 + (size_t)l*FF_DIM*D_DIM, w2t + (size_t)l*D_DIM*FF_DIM,
                       FF_DIM, D_DIM, tcur, nullptr, 0 };
        tcur += (FF_DIM/32)*(D_DIM/32); ++ti;
    }
    for (int e = 0; e < NEXP; ++e){
        ta.seg[ti] = { exp_w1 + (size_t)e*D_DIM*EH_DIM, e1t + (size_t)e*EH_DIM*D_DIM,
                       D_DIM, EH_DIM, tcur, nullptr, 0 };
        tcur += (D_DIM/32)*(EH_DIM/32); ++ti;
    }
    for (int e = 0; e < NEXP; ++e){
        ta.seg[ti] = { exp_w2 + (size_t)e*EH_DIM*D_DIM, e2t + (size_t)e*D_DIM*EH_DIM,
                       EH_DIM, D_DIM, tcur, nullptr, 0 };
        tcur += (EH_DIM/32)*(D_DIM/32); ++ti;
    }
    for (int l = 0; l < DEPTH; ++l){   // Wv^T scaled by ln1_w over dst row n (= h dim, axis 2)
        ta.seg[ti] = { inproj_w + (size_t)l*3*D_DIM*D_DIM + 2*D_DIM*D_DIM,
                       wvtbf + (size_t)l*D_DIM*D_DIM, D_DIM, D_DIM, tcur, ln1_w + l*D_DIM, 2 };
        tcur += (D_DIM/32)*(D_DIM/32); ++ti;
    }
    transpose_kernel<<<tcur, 256, 0, stream>>>(ta);

    // attn column constants: cca = Wo@(Wv@ln1_b + bv) + bo
    t2_kernel<<<DEPTH*D_DIM/4, 256, 0, stream>>>(inproj_w, inproj_b, ln1_b, t2buf);
    cca_kernel<<<DEPTH*D_DIM/4, 256, 0, stream>>>(outproj_w, outproj_b, t2buf, cca);
    // ffn1 column constants: ccf = ln2_b @ W1 + b1
    ccf_kernel<<<DEPTH*8, 256, 0, stream>>>(ffn_w1, ffn_b1, ln2_b, ccf);

    // wfold = Wo @ (ln1_w-scaled Wv)
    gemm_bt<<<48, 256, 0, stream>>>(
        wobf, wvtbf, zbias, wfold, 4, D_DIM, D_DIM,
        16, (size_t)D_DIM*D_DIM, (size_t)D_DIM*D_DIM, (size_t)D_DIM*D_DIM);

    // row sums of scaled weights: c1a (wfold), c1f (w1t)
    rowsum_kernel<<<(DEPTH*D_DIM + DEPTH*FF_DIM)/4, 256, 0, stream>>>(wfold, w1t, c1a, c1f);

    gemm_bt<<<(D_DIM/128)*(B_TOK/128), 256, 0, stream>>>(
        xbf, ebf, embed_b, h, D_DIM/128, D_DIM, IN_DIM,
        (D_DIM/128)*(B_TOK/128), 0, 0, 0);

    for (int l = 0; l < DEPTH; ++l){
        stats_kernel<<<B_TOK/4, 256, 0, stream>>>(h, mr);
        gemm256<G_LNRESID,0,0><<<(B_TOK/256)*(D_DIM/128), 512, 0, stream>>>(
            h, wfold + (size_t)l*D_DIM*D_DIM, cca + l*D_DIM, h,
            nullptr, nullptr, 0, 0, nullptr, mr, c1a + l*D_DIM,
            h, D_DIM/128, D_DIM, D_DIM);
        stats_kernel<<<B_TOK/4, 256, 0, stream>>>(h, mr);
        gemm256sq<<<(B_TOK/256)*(FF_DIM/256), 512, 0, stream>>>(
            h, w1t + (size_t)l*FF_DIM*D_DIM, ccf + l*FF_DIM, c1f + l*FF_DIM, mr,
            ubf, FF_DIM/256, FF_DIM, D_DIM);
        gemm256<G_BF16_RESID,0,0><<<(B_TOK/256)*(D_DIM/128), 512, 0, stream>>>(
            ubf, w2t + (size_t)l*D_DIM*FF_DIM, ffn_b2 + l*D_DIM, h,
            nullptr, nullptr, 0, 0, nullptr, nullptr, nullptr,
            h, D_DIM/128, D_DIM, FF_DIM);
    }

    router_kernel<<<B_TOK/4, 256, 0, stream>>>(h, router_w, router_b, idx2, wts2, bsums);
    aux_kernel<<<1, 256, 0, stream>>>(bsums, out + B_TOK);
    hist_kernel<<<NHBLK, 256, 0, stream>>>(idx2, blockHist);
    scan_kernel<<<1, 512, 0, stream>>>(blockHist, offs, baseArr);
    assign_kernel<<<B_TOK/256, 256, 0, stream>>>(idx2, wts2, baseArr, slot_map, gslot, tok);

    gemm256<G_GELU_BF16,1,1><<<MAXT256*(EH_DIM/128), 512, 0, stream>>>(
        h, e1t, exp_b1, nullptr, tok, offs, EH_DIM*D_DIM, EH_DIM, nullptr,
        nullptr, nullptr, hmidg, EH_DIM/128, EH_DIM, D_DIM);
    gemm256<G_GATED_BF16,1,0><<<MAXT256*(D_DIM/128), 512, 0, stream>>>(
        hmidg, e2t, exp_b2, nullptr, nullptr, offs, D_DIM*EH_DIM, D_DIM, gslot,
        nullptr, nullptr, eog, D_DIM/128, D_DIM, EH_DIM);

    head_kernel<<<B_TOK/4, 256, 0, stream>>>(h, eog, slot_map, head_ln_w, head_ln_b, head_w, head_b, out);
}

// Round 15
// 586.403 us; speedup vs baseline: 1.1921x; 1.1921x over previous
//
#include <hip/hip_runtime.h>
#include <hip/hip_bf16.h>

#define B_TOK 16384
#define IN_DIM 128
#define D_DIM 512
#define DEPTH 3
#define NEXP 8
#define FF_DIM 2048
#define EH_DIM 256
#define MAXSLOT 34816
#define MAXT256 136
#define NHBLK 64

typedef __attribute__((ext_vector_type(8))) __bf16 bf16x8;
typedef __attribute__((ext_vector_type(4))) float f32x4;
typedef __attribute__((ext_vector_type(4))) unsigned short u16x4;
typedef __attribute__((ext_vector_type(8))) unsigned short u16x8;

__device__ __forceinline__ unsigned short f2bf(float f){
    unsigned int u = __float_as_uint(f);
    u += 0x7fffu + ((u >> 16) & 1u);
    return (unsigned short)(u >> 16);
}
__device__ __forceinline__ float bf2f(unsigned short u){
    return __uint_as_float(((unsigned int)u) << 16);
}
__device__ __forceinline__ float geluf(float x){
    float x2 = x * x;
    float y  = x * (0.79788456080287f + 0.03567740814183f * x2);
    y = fminf(fmaxf(y, -15.0f), 15.0f);
    float e = __expf(2.0f * y);
    float th = 1.0f - 2.0f / (e + 1.0f);
    return 0.5f * x * (1.0f + th);
}
__device__ __forceinline__ void gload_lds16(const void* g, void* l){
    __builtin_amdgcn_global_load_lds((const __attribute__((address_space(1))) unsigned int*)g,
                                     (__attribute__((address_space(3))) unsigned int*)l,
                                     16, 0, 0);
}
__device__ __forceinline__ int xcd_swizzle(int orig, int nwg){
    const int q = nwg >> 3, r = nwg & 7;
    const int xcd = orig & 7;
    const int idx = orig >> 3;
    return (xcd < r ? xcd*(q+1) : r*(q+1) + (xcd-r)*q) + idx;
}

// ---------------- zero scratch control state ------------------------------
__global__ void zero_kernel(int* a, int na, int* b, int nb){
    const int i = blockIdx.x * blockDim.x + threadIdx.x;
    if (i < na) a[i] = 0;
    if (i < nb) b[i] = 0;
}

// ---------------- fp32 -> bf16 convert ------------------------------------
struct ConvSeg { const float* src; unsigned short* dst; int n4; };
struct ConvArgs { ConvSeg seg[2]; };

__global__ void convert_kernel(ConvArgs a){
    const int stride = gridDim.x * blockDim.x;
    const int tid = blockIdx.x * blockDim.x + threadIdx.x;
    for (int s = 0; s < 2; ++s){
        const f32x4* src = (const f32x4*)a.seg[s].src;
        u16x4* dst = (u16x4*)a.seg[s].dst;
        const int n4 = a.seg[s].n4;
        for (int i = tid; i < n4; i += stride){
            f32x4 v = src[i];
            u16x4 o;
            o[0] = f2bf(v[0]); o[1] = f2bf(v[1]); o[2] = f2bf(v[2]); o[3] = f2bf(v[3]);
            dst[i] = o;
        }
    }
}

// ------- weight transpose-convert with optional LN-gamma fold -------------
struct TSeg { const float* src; unsigned short* dst; int K; int N; int tileStart;
              const float* scl; int axis; };
struct TArgs { TSeg seg[26]; };

__global__ void transpose_kernel(TArgs a){
    __shared__ float t[32][33];
    const int tile = blockIdx.x;
    int s = 0;
    #pragma unroll 1
    while (s < 25 && tile >= a.seg[s+1].tileStart) ++s;
    const TSeg sg = a.seg[s];
    const int local = tile - sg.tileStart;
    const int tilesN = sg.N >> 5;
    const int k0 = (local / tilesN) << 5;
    const int n0 = (local % tilesN) << 5;
    const int tx = threadIdx.x & 31;
    const int ty = threadIdx.x >> 5;
    #pragma unroll
    for (int j = 0; j < 4; ++j)
        t[ty + j*8][tx] = sg.src[(size_t)(k0 + ty + j*8) * sg.N + n0 + tx];
    __syncthreads();
    const float sk = (sg.axis == 1) ? sg.scl[k0 + tx] : 1.0f;
    #pragma unroll
    for (int j = 0; j < 4; ++j){
        const int n = ty + j*8;
        float v = t[tx][n] * sk;
        if (sg.axis == 2) v *= sg.scl[n0 + n];
        sg.dst[(size_t)(n0 + n) * sg.K + k0 + tx] = f2bf(v);
    }
}

// ------- t2[l,j] = sum_k Wv[j,k]*ln1_b[l,k] + bv[l,j]  (wave per output) --
__global__ void t2_kernel(const float* __restrict__ inproj_w, const float* __restrict__ inproj_b,
                          const float* __restrict__ ln1_b, float* __restrict__ t2){
    const int wave = threadIdx.x >> 6, lane = threadIdx.x & 63;
    const int o = blockIdx.x * 4 + wave;
    const int l = o >> 9, j = o & 511;
    const float* Wv = inproj_w + (size_t)l*3*D_DIM*D_DIM + (size_t)2*D_DIM*D_DIM + (size_t)j*D_DIM;
    const float* b1 = ln1_b + l*D_DIM;
    float s = 0.f;
    #pragma unroll
    for (int q = 0; q < 8; ++q) s += Wv[lane + q*64] * b1[lane + q*64];
    #pragma unroll
    for (int off = 32; off > 0; off >>= 1) s += __shfl_xor(s, off);
    if (lane == 0) t2[o] = s + inproj_b[l*3*D_DIM + 2*D_DIM + j];
}

// ------- cca[l,n] = sum_j Wo[n,j]*t2[l,j] + bo[l,n]  (wave per output) ----
__global__ void cca_kernel(const float* __restrict__ outproj_w, const float* __restrict__ outproj_b,
                           const float* __restrict__ t2, float* __restrict__ cca){
    const int wave = threadIdx.x >> 6, lane = threadIdx.x & 63;
    const int o = blockIdx.x * 4 + wave;
    const int l = o >> 9, n = o & 511;
    const float* Wo = outproj_w + ((size_t)l*D_DIM + n)*D_DIM;
    const float* tt = t2 + l*D_DIM;
    float s = 0.f;
    #pragma unroll
    for (int q = 0; q < 8; ++q) s += Wo[lane + q*64] * tt[lane + q*64];
    #pragma unroll
    for (int off = 32; off > 0; off >>= 1) s += __shfl_xor(s, off);
    if (lane == 0) cca[o] = s + outproj_b[o];
}

// ------- row sums of scaled bf16 weights: c1a (wfold), c1f (w1t) ----------
__global__ void rowsum_kernel(const unsigned short* __restrict__ wfold,
                              const unsigned short* __restrict__ w1t,
                              float* __restrict__ c1a, float* __restrict__ c1f){
    const int wave = threadIdx.x >> 6, lane = threadIdx.x & 63;
    const int o = blockIdx.x * 4 + wave;
    const unsigned short* src;
    float* dst;
    if (o < DEPTH*D_DIM){ src = wfold + (size_t)o*D_DIM; dst = c1a + o; }
    else { src = w1t + (size_t)(o - DEPTH*D_DIM)*D_DIM; dst = c1f + (o - DEPTH*D_DIM); }
    u16x8 v = *(const u16x8*)(src + lane*8);
    float s = 0.f;
    #pragma unroll
    for (int q = 0; q < 8; ++q) s += bf2f(v[q]);
    #pragma unroll
    for (int off = 32; off > 0; off >>= 1) s += __shfl_xor(s, off);
    if (lane == 0) *dst = s;
}

// ------- ccf two-stage: part[l,kc,n] = sum over 32 k's; then reduce -------
__global__ void ccf_part_kernel(const float* __restrict__ ffn_w1, const float* __restrict__ ln2_b,
                                float* __restrict__ part){
    // grid: DEPTH*16*8 blocks; block = (l, kc 0..15, nc 0..7)
    const int b = blockIdx.x;
    const int l  = b >> 7;
    const int kc = (b >> 3) & 15;
    const int nc = b & 7;
    const int t = threadIdx.x;
    const float* W = ffn_w1 + (size_t)l*D_DIM*FF_DIM + (size_t)kc*32*FF_DIM + nc*256 + t;
    const float* lb = ln2_b + l*D_DIM + kc*32;
    float acc = 0.f;
    #pragma unroll 8
    for (int k = 0; k < 32; ++k) acc += lb[k] * W[(size_t)k*FF_DIM];
    part[((size_t)(l*16 + kc))*FF_DIM + nc*256 + t] = acc;
}

__global__ void ccf_red_kernel(const float* __restrict__ part, const float* __restrict__ ffn_b1,
                               float* __restrict__ ccf){
    // grid: DEPTH*8 blocks; block = (l, nc)
    const int l  = blockIdx.x >> 3;
    const int nc = blockIdx.x & 7;
    const int n  = nc*256 + threadIdx.x;
    float s = 0.f;
    #pragma unroll
    for (int kc = 0; kc < 16; ++kc) s += part[((size_t)(l*16 + kc))*FF_DIM + n];
    ccf[l*FF_DIM + n] = s + ffn_b1[l*FF_DIM + n];
}

// ---------------- small GEMM: 128x128, dbuf, bf16 out, layer-batched ------
__global__ void __launch_bounds__(256, 2)
gemm_bt(const unsigned short* __restrict__ A0, const unsigned short* __restrict__ Bt0,
        const float* __restrict__ bias, unsigned short* __restrict__ out0,
        int NB, int N, int K, int nper, size_t lsa, size_t lsb, size_t lsc)
{
    __shared__ unsigned short sh[32768];
    const int nwg = gridDim.x;
    int wg  = xcd_swizzle(blockIdx.x, nwg);
    const int layer = wg / nper;
    wg -= layer * nper;
    const unsigned short* A  = A0  + (size_t)layer * lsa;
    const unsigned short* Bt = Bt0 + (size_t)layer * lsb;
    unsigned short* out = out0 + (size_t)layer * lsc;
    const int bn  = wg % NB;
    const int bm  = wg / NB;

    const int tid  = threadIdx.x;
    const int lane = tid & 63;
    const int wave = tid >> 6;
    const int wm = (wave >> 1) << 6;
    const int wn = (wave & 1) << 6;

    f32x4 acc[4][4] = {};

    const unsigned short* Abase = A + (size_t)bm * 128 * K;
    const unsigned short* Bbase = Bt + (size_t)bn * 128 * K;
    const int soff = tid * 16;

    auto STAGE = [&](int b, int kt){
        char* Ab = (char*)(sh + b*16384);
        char* Bb = (char*)(sh + b*16384 + 8192);
        #pragma unroll
        for (int s = 0; s < 4; ++s){
            const int off = s*4096 + soff;
            const int row = off >> 7, colb = off & 127;
            gload_lds16((const char*)(Abase + (size_t)row*K + kt) + colb, Ab + off);
        }
        #pragma unroll
        for (int s = 0; s < 4; ++s){
            const int off = s*4096 + soff;
            const int row = off >> 7, colb = off & 127;
            gload_lds16((const char*)(Bbase + (size_t)row*K + kt) + colb, Bb + off);
        }
    };
    auto COMPUTE = [&](int b){
        const unsigned short* Ab = sh + b*16384;
        const unsigned short* Bb = sh + b*16384 + 8192;
        #pragma unroll
        for (int ks = 0; ks < 2; ++ks){
            const int k0 = ks*32 + ((lane>>4)<<3);
            bf16x8 af[4], bfr[4];
            #pragma unroll
            for (int i=0;i<4;i++) af[i]  = *(const bf16x8*)&Ab[(wm + i*16 + (lane&15))*64 + k0];
            #pragma unroll
            for (int j=0;j<4;j++) bfr[j] = *(const bf16x8*)&Bb[(wn + j*16 + (lane&15))*64 + k0];
            #pragma unroll
            for (int i=0;i<4;i++)
                #pragma unroll
                for (int j=0;j<4;j++)
                    acc[i][j] = __builtin_amdgcn_mfma_f32_16x16x32_bf16(af[i], bfr[j], acc[i][j], 0, 0, 0);
        }
    };

    STAGE(0, 0);
    __syncthreads();
    const int nk = K >> 6;
    int cur = 0;
    for (int i = 0; i < nk; ++i){
        if (i + 1 < nk) STAGE(cur ^ 1, (i + 1) << 6);
        COMPUTE(cur);
        __syncthreads();
        cur ^= 1;
    }

    const int r0 = ((lane>>4)<<2);
    const int cc = lane & 15;
    unsigned short* Ct = sh;
    float bcol[4];
    #pragma unroll
    for (int j=0;j<4;j++) bcol[j] = bias[bn*128 + wn + j*16 + cc];
    #pragma unroll
    for (int i=0;i<4;i++)
        #pragma unroll
        for (int r=0;r<4;r++){
            const int rl = wm + i*16 + r0 + r;
            #pragma unroll
            for (int j=0;j<4;j++)
                Ct[rl*128 + wn + j*16 + cc] = f2bf(acc[i][j][r] + bcol[j]);
        }
    __syncthreads();
    const int orow = tid >> 4;
    const int ocol = (tid & 15) * 8;
    #pragma unroll
    for (int p = 0; p < 8; ++p){
        const int row = p*16 + orow;
        *(u16x8*)(&out[(size_t)(bm*128 + row)*N + bn*128 + ocol]) = *(u16x8*)&Ct[row*128 + ocol];
    }
}

// ===== 256x256 GEMM 2-phase dbuf (ffn1): LN-fused epilogue ================
__global__ void __launch_bounds__(512, 2)
gemm256sq(const unsigned short* __restrict__ A, const unsigned short* __restrict__ Bt,
          const float* __restrict__ cc, const float* __restrict__ c1,
          const float2* __restrict__ mr, unsigned short* __restrict__ out,
          int NB, int N, int K)
{
    __shared__ __align__(16) char sh[131072];
    const int nwg = gridDim.x;
    const int wg  = xcd_swizzle(blockIdx.x, nwg);
    const int bn  = wg % NB;
    const int bm  = wg / NB;
    const int m0  = bm * 256;
    const int n0  = bn * 256;

    const int tid = threadIdx.x, lane = tid & 63, wave = tid >> 6;
    const int wr = wave >> 2;
    const int wc = wave & 3;

    const int srow = wave*16 + (lane >> 3);
    const int scol = ((lane & 7) ^ (lane >> 3)) * 8;
    const unsigned short* aptr[2][2];
    const unsigned short* bptr[2][2];
    #pragma unroll
    for (int u = 0; u < 2; ++u)
        #pragma unroll
        for (int l = 0; l < 2; ++l){
            aptr[u][l] = A  + (size_t)(m0 + u*128 + srow + l*8) * K + scol;
            bptr[u][l] = Bt + (size_t)(n0 + u*128 + srow + l*8) * K + scol;
        }
    const int sdst = wave*2048 + lane*16;

    int ch[2];
    #pragma unroll
    for (int ks = 0; ks < 2; ++ks)
        ch[ks] = ((((ks<<2) + (lane>>4)) ^ (lane & 7)) << 4);
    const int arow = wr*128 + (lane & 15);
    const int brow = wc*64  + (lane & 15);

    f32x4 acc[8][4] = {};

    auto STAGE = [&](int buf, int kt){
        #pragma unroll
        for (int u = 0; u < 2; ++u)
            #pragma unroll
            for (int l = 0; l < 2; ++l)
                gload_lds16(aptr[u][l] + kt, sh + buf*32768 + u*16384 + l*1024 + sdst);
        #pragma unroll
        for (int u = 0; u < 2; ++u)
            #pragma unroll
            for (int l = 0; l < 2; ++l)
                gload_lds16(bptr[u][l] + kt, sh + 65536 + buf*32768 + u*16384 + l*1024 + sdst);
    };
    auto COMPUTE = [&](int buf){
        bf16x8 bfr[4][2];
        #pragma unroll
        for (int nf = 0; nf < 4; ++nf)
            #pragma unroll
            for (int ks = 0; ks < 2; ++ks)
                bfr[nf][ks] = *(const bf16x8*)(sh + 65536 + buf*32768 + (brow + nf*16)*128 + ch[ks]);
        #pragma unroll
        for (int mf = 0; mf < 8; ++mf){
            bf16x8 af[2];
            #pragma unroll
            for (int ks = 0; ks < 2; ++ks)
                af[ks] = *(const bf16x8*)(sh + buf*32768 + (arow + mf*16)*128 + ch[ks]);
            #pragma unroll
            for (int nf = 0; nf < 4; ++nf)
                #pragma unroll
                for (int ks = 0; ks < 2; ++ks)
                    acc[mf][nf] = __builtin_amdgcn_mfma_f32_16x16x32_bf16(af[ks], bfr[nf][ks], acc[mf][nf], 0,0,0);
        }
    };

    STAGE(0, 0);
    __syncthreads();
    const int nk = K >> 6;
    int cur = 0;
    for (int i = 0; i < nk; ++i){
        if (i + 1 < nk) STAGE(cur ^ 1, (i + 1) << 6);
        COMPUTE(cur);
        __syncthreads();
        cur ^= 1;
    }

    unsigned short* Ct = (unsigned short*)sh;
    const int r4 = (lane >> 4) * 4;
    const int cc15 = lane & 15;
    float c1v[4], ccv[4];
    #pragma unroll
    for (int nf = 0; nf < 4; ++nf){
        const int col = n0 + wc*64 + nf*16 + cc15;
        c1v[nf] = c1[col];
        ccv[nf] = cc[col];
    }
    #pragma unroll
    for (int mf = 0; mf < 8; ++mf)
        #pragma unroll
        for (int r = 0; r < 4; ++r){
            const int row = wr*128 + mf*16 + r4 + r;
            const float2 m = mr[m0 + row];
            #pragma unroll
            for (int nf = 0; nf < 4; ++nf){
                const int col = wc*64 + nf*16 + cc15;
                Ct[row*256 + col] = f2bf(geluf(m.x*acc[mf][nf][r] - m.y*c1v[nf] + ccv[nf]));
            }
        }
    __syncthreads();
    #pragma unroll
    for (int p = 0; p < 16; ++p){
        const int uidx = p*512 + tid;
        const int row = uidx >> 5;
        const int cu  = uidx & 31;
        *(u16x8*)(out + (size_t)(m0 + row)*N + n0 + cu*8) = *(const u16x8*)(Ct + row*256 + cu*8);
    }
}

// =================== 256x128 2-phase GEMM =================================
#define G_GELU_BF16 0
#define G_BF16_RESID 1
#define G_GATED_BF16 2
#define G_LNRESID 3

template<int EPI, int MOE, int INDIRECT>
__global__ void __launch_bounds__(512, 2)
gemm256(const unsigned short* __restrict__ A, const unsigned short* __restrict__ BtG,
        const float* __restrict__ biasG, const unsigned short* __restrict__ resid,
        const int* __restrict__ tok, const int* __restrict__ offs,
        int wstride, int bstride, const float* __restrict__ gslot,
        const float2* __restrict__ mr, const float* __restrict__ c1,
        unsigned short* __restrict__ out, int NB, int N, int K)
{
    __shared__ __align__(16) char sh[147456];
    const int nwg = gridDim.x;
    const int wg  = xcd_swizzle(blockIdx.x, nwg);
    const int bn  = wg % NB;
    const int bm  = wg / NB;
    const int m0  = bm * 256;

    const unsigned short* Bt = BtG;
    const float* bias = biasG;
    if (MOE){
        if (m0 >= offs[8]) return;
        int e = 0;
        #pragma unroll 1
        while (offs[e+1] <= m0) ++e;
        Bt   += (size_t)e * wstride;
        bias += (size_t)e * bstride;
    }

    const int tid = threadIdx.x, lane = tid & 63, wave = tid >> 6;
    const int wm = (wave >> 1) * 64;
    const int wn = (wave & 1) * 64;

    const int srow = wave*16 + (lane >> 3);
    const int scol = ((lane & 7) ^ (lane >> 3)) * 8;
    const unsigned short* aptr[2][2];
    #pragma unroll
    for (int u = 0; u < 2; ++u)
        #pragma unroll
        for (int l = 0; l < 2; ++l){
            const int r = u*128 + srow + l*8;
            const int gr = INDIRECT ? tok[m0 + r] : (m0 + r);
            aptr[u][l] = A + (size_t)gr * K + scol;
        }
    const unsigned short* bptr[2];
    #pragma unroll
    for (int l = 0; l < 2; ++l)
        bptr[l] = Bt + (size_t)(bn*128 + srow + l*8) * K + scol;
    const int sdst = wave*2048 + lane*16;

    int aoff[2], boff[2];
    #pragma unroll
    for (int ks = 0; ks < 2; ++ks){
        const int ch = (((ks<<2) + (lane>>4)) ^ (lane & 7)) << 4;
        aoff[ks] = (wm + (lane & 15))*128 + ch;
        boff[ks] = (wn + (lane & 15))*128 + ch;
    }

    f32x4 acc[4][4] = {};

    auto STAGE = [&](int buf, int kt){
        #pragma unroll
        for (int u = 0; u < 2; ++u)
            #pragma unroll
            for (int l = 0; l < 2; ++l)
                gload_lds16(aptr[u][l] + kt, sh + buf*32768 + u*16384 + l*1024 + sdst);
        #pragma unroll
        for (int l = 0; l < 2; ++l)
            gload_lds16(bptr[l] + kt, sh + 98304 + buf*16384 + l*1024 + sdst);
    };
    auto COMPUTE = [&](int buf){
        bf16x8 bfr[4][2];
        #pragma unroll
        for (int nf = 0; nf < 4; ++nf)
            #pragma unroll
            for (int ks = 0; ks < 2; ++ks)
                bfr[nf][ks] = *(const bf16x8*)(sh + 98304 + buf*16384 + nf*2048 + boff[ks]);
        #pragma unroll
        for (int mf = 0; mf < 4; ++mf){
            bf16x8 af[2];
            #pragma unroll
            for (int ks = 0; ks < 2; ++ks)
                af[ks] = *(const bf16x8*)(sh + buf*32768 + mf*2048 + aoff[ks]);
            #pragma unroll
            for (int nf = 0; nf < 4; ++nf)
                #pragma unroll
                for (int ks = 0; ks < 2; ++ks)
                    acc[mf][nf] = __builtin_amdgcn_mfma_f32_16x16x32_bf16(af[ks], bfr[nf][ks], acc[mf][nf], 0,0,0);
        }
    };

    STAGE(0, 0);
    __syncthreads();
    const int nk = K >> 6;
    int cur = 0;
    for (int i = 0; i < nk; ++i){
        if (i + 1 < nk) STAGE(cur ^ 1, (i + 1) << 6);
        COMPUTE(cur);
        __syncthreads();
        cur ^= 1;
    }

    const int r4 = (lane >> 4) * 4;
    const int cc15 = lane & 15;
    if (EPI == G_BF16_RESID || EPI == G_LNRESID){
        float* ctf = (float*)sh;
        float bcol[4], c1v[4];
        #pragma unroll
        for (int nf = 0; nf < 4; ++nf){
            bcol[nf] = bias[bn*128 + wn + nf*16 + cc15];
            if (EPI == G_LNRESID) c1v[nf] = c1[bn*128 + wn + nf*16 + cc15];
        }
        #pragma unroll
        for (int mf = 0; mf < 4; ++mf)
            #pragma unroll
            for (int r = 0; r < 4; ++r){
                const int row = wm + mf*16 + r4 + r;
                float2 m = make_float2(1.f, 0.f);
                if (EPI == G_LNRESID) m = mr[m0 + row];
                #pragma unroll
                for (int nf = 0; nf < 4; ++nf){
                    float v;
                    if (EPI == G_LNRESID) v = m.x*acc[mf][nf][r] - m.y*c1v[nf] + bcol[nf];
                    else                  v = acc[mf][nf][r] + bcol[nf];
                    ctf[row*128 + wn + nf*16 + cc15] = v;
                }
            }
        __syncthreads();
        #pragma unroll
        for (int p = 0; p < 8; ++p){
            const int uidx = p*512 + tid;
            const int row = uidx >> 4;
            const int cu  = uidx & 15;
            const size_t gidx = (size_t)(m0 + row)*N + bn*128 + cu*8;
            u16x8 hv = *(const u16x8*)(resid + gidx);
            u16x8 o;
            #pragma unroll
            for (int j = 0; j < 8; ++j)
                o[j] = f2bf(bf2f(hv[j]) + ctf[row*128 + cu*8 + j]);
            *(u16x8*)(out + gidx) = o;
        }
    } else {
        unsigned short* ct = (unsigned short*)sh;
        #pragma unroll
        for (int nf = 0; nf < 4; ++nf){
            const float bv = bias[bn*128 + wn + nf*16 + cc15];
            #pragma unroll
            for (int mf = 0; mf < 4; ++mf)
                #pragma unroll
                for (int r = 0; r < 4; ++r){
                    const int row = wm + mf*16 + r4 + r;
                    float v = acc[mf][nf][r] + bv;
                    if (EPI == G_GELU_BF16) v = geluf(v);
                    else                    v *= gslot[m0 + row];
                    ct[row*128 + wn + nf*16 + cc15] = f2bf(v);
                }
        }
        __syncthreads();
        #pragma unroll
        for (int p = 0; p < 8; ++p){
            const int uidx = p*512 + tid;
            const int row = uidx >> 4;
            const int cu  = uidx & 15;
            *(u16x8*)(out + (size_t)(m0 + row)*N + bn*128 + cu*8) =
                *(const u16x8*)(ct + row*128 + cu*8);
        }
    }
}

// ---------------- LN stats only: mr[row] = {1/sigma, mean/sigma} ----------
__global__ void stats_kernel(const unsigned short* __restrict__ x, float2* __restrict__ mr)
{
    const int lane = threadIdx.x & 63;
    const int wave = threadIdx.x >> 6;
    const int row  = blockIdx.x * 4 + wave;
    u16x8 hv = *(const u16x8*)(x + (size_t)row * D_DIM + lane*8);
    float s = 0.f, s2 = 0.f;
    #pragma unroll
    for (int j = 0; j < 8; ++j){ const float v = bf2f(hv[j]); s += v; s2 += v*v; }
    #pragma unroll
    for (int o = 32; o > 0; o >>= 1){ s += __shfl_xor(s, o); s2 += __shfl_xor(s2, o); }
    if (lane == 0){
        const float mean = s * (1.0f/512.0f);
        const float var  = s2 * (1.0f/512.0f) - mean*mean;
        const float inv  = 1.0f / sqrtf(var + 1e-5f);
        mr[row] = make_float2(inv, mean*inv);
    }
}

// ------- Router: softmax+eps-mix+top2 (bf16 z in, no global atomics) ------
__global__ void router_kernel(const unsigned short* __restrict__ z, const float* __restrict__ rw,
                              const float* __restrict__ rb,
                              int2* __restrict__ idx2, float2* __restrict__ wts2,
                              float* __restrict__ bsums)
{
    __shared__ float ps[4][8];
    const int lane = threadIdx.x & 63;
    const int wave = threadIdx.x >> 6;
    const int row  = blockIdx.x * 4 + wave;
    u16x8 hv = *(const u16x8*)(z + (size_t)row * D_DIM + lane*8);
    float acc[8] = {0,0,0,0,0,0,0,0};
    #pragma unroll
    for (int j = 0; j < 8; ++j){
        const float zv = bf2f(hv[j]);
        const float* wr = rw + (size_t)(lane*8 + j) * 8;
        f32x4 w0 = *(const f32x4*)wr;
        f32x4 w1 = *(const f32x4*)(wr + 4);
        acc[0] += zv*w0[0]; acc[1] += zv*w0[1]; acc[2] += zv*w0[2]; acc[3] += zv*w0[3];
        acc[4] += zv*w1[0]; acc[5] += zv*w1[1]; acc[6] += zv*w1[2]; acc[7] += zv*w1[3];
    }
    #pragma unroll
    for (int o = 32; o > 0; o >>= 1){
        #pragma unroll
        for (int e = 0; e < 8; ++e) acc[e] += __shfl_xor(acc[e], o);
    }
    if (lane == 0){
        float p[8]; float mx = -1e30f;
        #pragma unroll
        for (int e=0;e<8;e++){ p[e] = acc[e] + rb[e]; mx = fmaxf(mx, p[e]); }
        float se = 0.f;
        #pragma unroll
        for (int e=0;e<8;e++){ p[e] = expf(p[e]-mx); se += p[e]; }
        const float sc = 0.9f / se;
        #pragma unroll
        for (int e=0;e<8;e++) p[e] = p[e]*sc + 0.0125f;
        int i1 = 0;
        #pragma unroll
        for (int e=1;e<8;e++) if (p[e] > p[i1]) i1 = e;
        int i2 = (i1 == 0) ? 1 : 0;
        for (int e=i2+1;e<8;e++) if (e != i1 && p[e] > p[i2]) i2 = e;
        idx2[row] = make_int2(i1, i2);
        wts2[row] = make_float2(p[i1], p[i2]);
        #pragma unroll
        for (int e=0;e<8;e++) ps[wave][e] = p[e];
    }
    __syncthreads();
    if (threadIdx.x < 8){
        bsums[blockIdx.x*8 + threadIdx.x] =
            ps[0][threadIdx.x] + ps[1][threadIdx.x] + ps[2][threadIdx.x] + ps[3][threadIdx.x];
    }
}

// ------- histogram / scan / assign (block-local, no global atomics) -------
__global__ void hist_kernel(const int2* __restrict__ idx2, int* __restrict__ blockHist){
    __shared__ int hc[8];
    if (threadIdx.x < 8) hc[threadIdx.x] = 0;
    __syncthreads();
    const int t = blockIdx.x * 256 + threadIdx.x;
    const int2 ii = idx2[t];
    atomicAdd(&hc[ii.x], 1);
    atomicAdd(&hc[ii.y], 1);
    __syncthreads();
    if (threadIdx.x < 8) blockHist[blockIdx.x*8 + threadIdx.x] = hc[threadIdx.x];
}

__global__ void scan_kernel(const int* __restrict__ blockHist, int* __restrict__ offs,
                            int* __restrict__ baseArr){
    __shared__ int hist[NHBLK*8];
    __shared__ int cnt[8];
    __shared__ int start[8];
    const int t = threadIdx.x;
    hist[t] = blockHist[t];
    __syncthreads();
    if (t < 8){
        int c = 0;
        #pragma unroll 1
        for (int b = 0; b < NHBLK; ++b) c += hist[b*8 + t];
        cnt[t] = c;
    }
    __syncthreads();
    if (t == 0){
        int o = 0; offs[0] = 0;
        for (int e = 0; e < 8; ++e){ start[e] = o; o += (cnt[e]+255)&~255; offs[e+1] = o; }
    }
    __syncthreads();
    if (t < 8){
        int cur = start[t];
        #pragma unroll 1
        for (int b = 0; b < NHBLK; ++b){ baseArr[b*8 + t] = cur; cur += hist[b*8 + t]; }
    }
}

__global__ void assign_kernel(const int2* __restrict__ idx2, const float2* __restrict__ wts2,
                              const int* __restrict__ baseArr, int2* __restrict__ slot_map,
                              float* __restrict__ gslot, int* __restrict__ tok)
{
    __shared__ int cur[8];
    if (threadIdx.x < 8) cur[threadIdx.x] = 0;
    __syncthreads();
    const int t = blockIdx.x * 256 + threadIdx.x;
    const int2 ii = idx2[t];
    const float2 ww = wts2[t];
    const int r1 = atomicAdd(&cur[ii.x], 1);
    const int r2 = atomicAdd(&cur[ii.y], 1);
    const int s1 = baseArr[blockIdx.x*8 + ii.x] + r1;
    const int s2 = baseArr[blockIdx.x*8 + ii.y] + r2;
    slot_map[t] = make_int2(s1, s2);
    gslot[s1] = ww.x; gslot[s2] = ww.y;
    tok[s1] = t; tok[s2] = t;
}

// ---------------- aux loss ------------------------------------------------
__global__ void aux_kernel(const float* __restrict__ bsums, float* __restrict__ out_aux)
{
    __shared__ float part[256];
    const int t = threadIdx.x;
    const int e = t & 7, chunk = t >> 3;
    float s = 0.f;
    for (int blk = chunk*128; blk < chunk*128 + 128; ++blk) s += bsums[blk*8 + e];
    part[t] = s;
    __syncthreads();
    if (t < 8){
        float tot = 0.f;
        for (int c = 0; c < 32; ++c) tot += part[c*8 + t];
        part[t] = tot;
    }
    __syncthreads();
    if (t == 0){
        float aux = 0.f;
        for (int e2 = 0; e2 < 8; ++e2){
            float load = part[e2] * (1.0f/16384.0f);
            aux += load * logf(load * 8.0f + 1e-9f);
        }
        out_aux[0] = aux / 2.0794415416798357f;
    }
}

// -------- head: z = h + eo[s1] + eo[s2]; LN; dot --------------------------
__global__ void head_kernel(const unsigned short* __restrict__ h, const unsigned short* __restrict__ eog,
                            const int2* __restrict__ slot_map,
                            const float* __restrict__ w, const float* __restrict__ b,
                            const float* __restrict__ hw, const float* __restrict__ hb,
                            float* __restrict__ out)
{
    const int lane = threadIdx.x & 63;
    const int wave = threadIdx.x >> 6;
    const int row  = blockIdx.x * 4 + wave;
    const int2 sm = slot_map[row];
    u16x8 hv = *(const u16x8*)(h + (size_t)row * D_DIM + lane*8);
    u16x8 e1 = *(const u16x8*)(eog + (size_t)sm.x * D_DIM + lane*8);
    u16x8 e2 = *(const u16x8*)(eog + (size_t)sm.y * D_DIM + lane*8);
    float v[8];
    #pragma unroll
    for (int j=0;j<8;j++) v[j] = bf2f(hv[j]) + bf2f(e1[j]) + bf2f(e2[j]);
    float s = 0.f, s2 = 0.f;
    #pragma unroll
    for (int j=0;j<8;j++){ s += v[j]; s2 += v[j]*v[j]; }
    #pragma unroll
    for (int o = 32; o > 0; o >>= 1){ s += __shfl_xor(s, o); s2 += __shfl_xor(s2, o); }
    const float mean = s * (1.0f/512.0f);
    const float var  = s2 * (1.0f/512.0f) - mean*mean;
    const float inv  = 1.0f / sqrtf(var + 1e-5f);
    const int k = lane*8;
    float dot = 0.f;
    #pragma unroll
    for (int j=0;j<8;j++) dot += ((v[j]-mean)*inv*w[k+j] + b[k+j]) * hw[k+j];
    #pragma unroll
    for (int o = 32; o > 0; o >>= 1) dot += __shfl_xor(dot, o);
    if (lane == 0) out[row] = dot + hb[0];
}

// ===========================================================================
extern "C" void kernel_launch(void* const* d_in, const int* in_sizes, int n_in,
                              void* d_out, int out_size, void* d_ws, size_t ws_size,
                              hipStream_t stream)
{
    (void)in_sizes; (void)n_in; (void)out_size; (void)ws_size;
    const float* x         = (const float*)d_in[0];
    const float* embed_w   = (const float*)d_in[1];
    const float* embed_b   = (const float*)d_in[2];
    const float* ln1_w     = (const float*)d_in[3];
    const float* ln1_b     = (const float*)d_in[4];
    const float* inproj_w  = (const float*)d_in[5];
    const float* inproj_b  = (const float*)d_in[6];
    const float* outproj_w = (const float*)d_in[7];
    const float* outproj_b = (const float*)d_in[8];
    const float* ln2_w     = (const float*)d_in[9];
    const float* ln2_b     = (const float*)d_in[10];
    const float* ffn_w1    = (const float*)d_in[11];
    const float* ffn_b1    = (const float*)d_in[12];
    const float* ffn_w2    = (const float*)d_in[13];
    const float* ffn_b2    = (const float*)d_in[14];
    const float* router_w  = (const float*)d_in[15];
    const float* router_b  = (const float*)d_in[16];
    const float* exp_w1    = (const float*)d_in[17];
    const float* exp_b1    = (const float*)d_in[18];
    const float* exp_w2    = (const float*)d_in[19];
    const float* exp_b2    = (const float*)d_in[20];
    const float* head_ln_w = (const float*)d_in[21];
    const float* head_ln_b = (const float*)d_in[22];
    const float* head_w    = (const float*)d_in[23];
    const float* head_b    = (const float*)d_in[24];

    char* ws = (char*)d_ws;
    unsigned short* xbf   = (unsigned short*)(ws + 0);
    unsigned short* ebf   = (unsigned short*)(ws + 4194304);
    unsigned short* wobf  = (unsigned short*)(ws + 4325376);
    unsigned short* wvtbf = (unsigned short*)(ws + 5898240);
    unsigned short* wfold = (unsigned short*)(ws + 7471104);
    unsigned short* w1t   = (unsigned short*)(ws + 9043968);
    unsigned short* w2t   = (unsigned short*)(ws + 15335424);
    unsigned short* e1t   = (unsigned short*)(ws + 21626880);
    unsigned short* e2t   = (unsigned short*)(ws + 23724032);
    unsigned short* h     = (unsigned short*)(ws + 25821184);
    unsigned short* ubf   = (unsigned short*)(ws + 59375616);
    unsigned short* hmidg = ubf;
    unsigned short* eog   = (unsigned short*)(ws + 77201408);
    char* MISC = ws + 126484480;
    int*    offs     = (int*)(MISC + 0);
    float*  zbias    = (float*)(MISC + 256);
    int2*   idx2     = (int2*)(MISC + 8448);
    float2* wts2     = (float2*)(MISC + 139520);
    int2*   slot_map = (int2*)(MISC + 270592);
    float*  gslot    = (float*)(MISC + 401664);
    int*    tok      = (int*)(MISC + 544768);
    float*  bsums    = (float*)(MISC + 684032);
    int*    blockHist= (int*)(MISC + 815104);
    int*    baseArr  = (int*)(MISC + 817152);
    float2* mr       = (float2*)(MISC + 860160);   // 131072
    float*  t2buf    = (float*)(MISC + 991232);    //   6144
    float*  cca      = (float*)(MISC + 997376);    //   6144
    float*  c1a      = (float*)(MISC + 1003520);   //   6144
    float*  c1f      = (float*)(MISC + 1009664);   //  24576
    float*  ccf      = (float*)(MISC + 1034240);   //  24576
    float*  ccfp     = (float*)(MISC + 1058816);   // 393216 partials
    float* out = (float*)d_out;

    zero_kernel<<<(MAXSLOT + 255)/256, 256, 0, stream>>>((int*)zbias, 512, tok, MAXSLOT);

    ConvArgs ca;
    ca.seg[0] = { x, xbf, B_TOK*IN_DIM/4 };
    ca.seg[1] = { outproj_w, wobf, DEPTH*D_DIM*D_DIM/4 };
    convert_kernel<<<1024, 256, 0, stream>>>(ca);

    TArgs ta;
    int tcur = 0, ti = 0;
    ta.seg[ti] = { embed_w, ebf, IN_DIM, D_DIM, tcur, nullptr, 0 };
    tcur += (IN_DIM/32)*(D_DIM/32); ++ti;
    for (int l = 0; l < DEPTH; ++l){
        ta.seg[ti] = { ffn_w1 + (size_t)l*D_DIM*FF_DIM, w1t + (size_t)l*FF_DIM*D_DIM,
                       D_DIM, FF_DIM, tcur, ln2_w + l*D_DIM, 1 };
        tcur += (D_DIM/32)*(FF_DIM/32); ++ti;
    }
    for (int l = 0; l < DEPTH; ++l){
        ta.seg[ti] = { ffn_w2 + (size_t)l*FF_DIM*D_DIM, w2t + (size_t)l*D_DIM*FF_DIM,
                       FF_DIM, D_DIM, tcur, nullptr, 0 };
        tcur += (FF_DIM/32)*(D_DIM/32); ++ti;
    }
    for (int e = 0; e < NEXP; ++e){
        ta.seg[ti] = { exp_w1 + (size_t)e*D_DIM*EH_DIM, e1t + (size_t)e*EH_DIM*D_DIM,
                       D_DIM, EH_DIM, tcur, nullptr, 0 };
        tcur += (D_DIM/32)*(EH_DIM/32); ++ti;
    }
    for (int e = 0; e < NEXP; ++e){
        ta.seg[ti] = { exp_w2 + (size_t)e*EH_DIM*D_DIM, e2t + (size_t)e*D_DIM*EH_DIM,
                       EH_DIM, D_DIM, tcur, nullptr, 0 };
        tcur += (EH_DIM/32)*(D_DIM/32); ++ti;
    }
    for (int l = 0; l < DEPTH; ++l){
        ta.seg[ti] = { inproj_w + (size_t)l*3*D_DIM*D_DIM + 2*D_DIM*D_DIM,
                       wvtbf + (size_t)l*D_DIM*D_DIM, D_DIM, D_DIM, tcur, ln1_w + l*D_DIM, 2 };
        tcur += (D_DIM/32)*(D_DIM/32); ++ti;
    }
    transpose_kernel<<<tcur, 256, 0, stream>>>(ta);

    t2_kernel<<<DEPTH*D_DIM/4, 256, 0, stream>>>(inproj_w, inproj_b, ln1_b, t2buf);
    cca_kernel<<<DEPTH*D_DIM/4, 256, 0, stream>>>(outproj_w, outproj_b, t2buf, cca);
    ccf_part_kernel<<<DEPTH*16*8, 256, 0, stream>>>(ffn_w1, ln2_b, ccfp);
    ccf_red_kernel<<<DEPTH*8, 256, 0, stream>>>(ccfp, ffn_b1, ccf);

    gemm_bt<<<48, 256, 0, stream>>>(
        wobf, wvtbf, zbias, wfold, 4, D_DIM, D_DIM,
        16, (size_t)D_DIM*D_DIM, (size_t)D_DIM*D_DIM, (size_t)D_DIM*D_DIM);

    rowsum_kernel<<<(DEPTH*D_DIM + DEPTH*FF_DIM)/4, 256, 0, stream>>>(wfold, w1t, c1a, c1f);

    gemm_bt<<<(D_DIM/128)*(B_TOK/128), 256, 0, stream>>>(
        xbf, ebf, embed_b, h, D_DIM/128, D_DIM, IN_DIM,
        (D_DIM/128)*(B_TOK/128), 0, 0, 0);

    for (int l = 0; l < DEPTH; ++l){
        stats_kernel<<<B_TOK/4, 256, 0, stream>>>(h, mr);
        gemm256<G_LNRESID,0,0><<<(B_TOK/256)*(D_DIM/128), 512, 0, stream>>>(
            h, wfold + (size_t)l*D_DIM*D_DIM, cca + l*D_DIM, h,
            nullptr, nullptr, 0, 0, nullptr, mr, c1a + l*D_DIM,
            h, D_DIM/128, D_DIM, D_DIM);
        stats_kernel<<<B_TOK/4, 256, 0, stream>>>(h, mr);
        gemm256sq<<<(B_TOK/256)*(FF_DIM/256), 512, 0, stream>>>(
            h, w1t + (size_t)l*FF_DIM*D_DIM, ccf + l*FF_DIM, c1f + l*FF_DIM, mr,
            ubf, FF_DIM/256, FF_DIM, D_DIM);
        gemm256<G_BF16_RESID,0,0><<<(B_TOK/256)*(D_DIM/128), 512, 0, stream>>>(
            ubf, w2t + (size_t)l*D_DIM*FF_DIM, ffn_b2 + l*D_DIM, h,
            nullptr, nullptr, 0, 0, nullptr, nullptr, nullptr,
            h, D_DIM/128, D_DIM, FF_DIM);
    }

    router_kernel<<<B_TOK/4, 256, 0, stream>>>(h, router_w, router_b, idx2, wts2, bsums);
    aux_kernel<<<1, 256, 0, stream>>>(bsums, out + B_TOK);
    hist_kernel<<<NHBLK, 256, 0, stream>>>(idx2, blockHist);
    scan_kernel<<<1, 512, 0, stream>>>(blockHist, offs, baseArr);
    assign_kernel<<<B_TOK/256, 256, 0, stream>>>(idx2, wts2, baseArr, slot_map, gslot, tok);

    gemm256<G_GELU_BF16,1,1><<<MAXT256*(EH_DIM/128), 512, 0, stream>>>(
        h, e1t, exp_b1, nullptr, tok, offs, EH_DIM*D_DIM, EH_DIM, nullptr,
        nullptr, nullptr, hmidg, EH_DIM/128, EH_DIM, D_DIM);
    gemm256<G_GATED_BF16,1,0><<<MAXT256*(D_DIM/128), 512, 0, stream>>>(
        hmidg, e2t, exp_b2, nullptr, nullptr, offs, D_DIM*EH_DIM, D_DIM, gslot,
        nullptr, nullptr, eog, D_DIM/128, D_DIM, EH_DIM);

    head_kernel<<<B_TOK/4, 256, 0, stream>>>(h, eog, slot_map, head_ln_w, head_ln_b, head_w, head_b, out);
}

// Round 16
// 573.084 us; speedup vs baseline: 1.2198x; 1.0232x over previous
//
#include <hip/hip_runtime.h>
#include <hip/hip_bf16.h>

#define B_TOK 16384
#define IN_DIM 128
#define D_DIM 512
#define DEPTH 3
#define NEXP 8
#define FF_DIM 2048
#define EH_DIM 256
#define MAXSLOT 34816
#define MAXT256 136
#define NHBLK 64

typedef __attribute__((ext_vector_type(8))) __bf16 bf16x8;
typedef __attribute__((ext_vector_type(4))) float f32x4;
typedef __attribute__((ext_vector_type(4))) unsigned short u16x4;
typedef __attribute__((ext_vector_type(8))) unsigned short u16x8;

__device__ __forceinline__ unsigned short f2bf(float f){
    unsigned int u = __float_as_uint(f);
    u += 0x7fffu + ((u >> 16) & 1u);
    return (unsigned short)(u >> 16);
}
__device__ __forceinline__ float bf2f(unsigned short u){
    return __uint_as_float(((unsigned int)u) << 16);
}
__device__ __forceinline__ float geluf(float x){
    float x2 = x * x;
    float y  = x * (0.79788456080287f + 0.03567740814183f * x2);
    y = fminf(fmaxf(y, -15.0f), 15.0f);
    float e = __expf(2.0f * y);
    float th = 1.0f - 2.0f / (e + 1.0f);
    return 0.5f * x * (1.0f + th);
}
__device__ __forceinline__ void gload_lds16(const void* g, void* l){
    __builtin_amdgcn_global_load_lds((const __attribute__((address_space(1))) unsigned int*)g,
                                     (__attribute__((address_space(3))) unsigned int*)l,
                                     16, 0, 0);
}
__device__ __forceinline__ int xcd_swizzle(int orig, int nwg){
    const int q = nwg >> 3, r = nwg & 7;
    const int xcd = orig & 7;
    const int idx = orig >> 3;
    return (xcd < r ? xcd*(q+1) : r*(q+1) + (xcd-r)*q) + idx;
}

// ---------------- zero scratch control state ------------------------------
__global__ void zero_kernel(int* a, int na, int* b, int nb){
    const int i = blockIdx.x * blockDim.x + threadIdx.x;
    if (i < na) a[i] = 0;
    if (i < nb) b[i] = 0;
}

// ---------------- fp32 -> bf16 convert ------------------------------------
struct ConvSeg { const float* src; unsigned short* dst; int n4; };
struct ConvArgs { ConvSeg seg[2]; };

__global__ void convert_kernel(ConvArgs a){
    const int stride = gridDim.x * blockDim.x;
    const int tid = blockIdx.x * blockDim.x + threadIdx.x;
    for (int s = 0; s < 2; ++s){
        const f32x4* src = (const f32x4*)a.seg[s].src;
        u16x4* dst = (u16x4*)a.seg[s].dst;
        const int n4 = a.seg[s].n4;
        for (int i = tid; i < n4; i += stride){
            f32x4 v = src[i];
            u16x4 o;
            o[0] = f2bf(v[0]); o[1] = f2bf(v[1]); o[2] = f2bf(v[2]); o[3] = f2bf(v[3]);
            dst[i] = o;
        }
    }
}

// ------------- weight transpose-convert: (K,N) fp32 -> (N,K) bf16 ---------
struct TSeg { const float* src; unsigned short* dst; int K; int N; int tileStart; };
struct TArgs { TSeg seg[26]; };

__global__ void transpose_kernel(TArgs a){
    __shared__ float t[32][33];
    const int tile = blockIdx.x;
    int s = 0;
    #pragma unroll 1
    while (s < 25 && tile >= a.seg[s+1].tileStart) ++s;
    const TSeg sg = a.seg[s];
    const int local = tile - sg.tileStart;
    const int tilesN = sg.N >> 5;
    const int k0 = (local / tilesN) << 5;
    const int n0 = (local % tilesN) << 5;
    const int tx = threadIdx.x & 31;
    const int ty = threadIdx.x >> 5;
    #pragma unroll
    for (int j = 0; j < 4; ++j)
        t[ty + j*8][tx] = sg.src[(size_t)(k0 + ty + j*8) * sg.N + n0 + tx];
    __syncthreads();
    #pragma unroll
    for (int j = 0; j < 4; ++j){
        const int n = ty + j*8;
        sg.dst[(size_t)(n0 + n) * sg.K + k0 + tx] = f2bf(t[tx][n]);
    }
}

// ------- folded attention bias: bfold = Wo@bv + bo (wave per output) ------
__global__ void foldb_kernel(const float* __restrict__ outproj_w, const float* __restrict__ outproj_b,
                             const float* __restrict__ inproj_b, float* __restrict__ bfold){
    const int wave = threadIdx.x >> 6, lane = threadIdx.x & 63;
    const int o = blockIdx.x * 4 + wave;
    const int l = o >> 9, n = o & 511;
    const float* Wo = outproj_w + ((size_t)l*D_DIM + n)*D_DIM;
    const float* bv = inproj_b + l*3*D_DIM + 2*D_DIM;
    float s = 0.f;
    #pragma unroll
    for (int j = 0; j < 8; ++j) s += Wo[lane + j*64] * bv[lane + j*64];
    #pragma unroll
    for (int off = 32; off > 0; off >>= 1) s += __shfl_xor(s, off);
    if (lane == 0) bfold[o] = s + outproj_b[o];
}

// ---------------- small GEMM: 128x128, dbuf, bf16 out, layer-batched ------
__global__ void __launch_bounds__(256, 2)
gemm_bt(const unsigned short* __restrict__ A0, const unsigned short* __restrict__ Bt0,
        const float* __restrict__ bias, unsigned short* __restrict__ out0,
        int NB, int N, int K, int nper, size_t lsa, size_t lsb, size_t lsc)
{
    __shared__ unsigned short sh[32768];
    const int nwg = gridDim.x;
    int wg  = xcd_swizzle(blockIdx.x, nwg);
    const int layer = wg / nper;
    wg -= layer * nper;
    const unsigned short* A  = A0  + (size_t)layer * lsa;
    const unsigned short* Bt = Bt0 + (size_t)layer * lsb;
    unsigned short* out = out0 + (size_t)layer * lsc;
    const int bn  = wg % NB;
    const int bm  = wg / NB;

    const int tid  = threadIdx.x;
    const int lane = tid & 63;
    const int wave = tid >> 6;
    const int wm = (wave >> 1) << 6;
    const int wn = (wave & 1) << 6;

    f32x4 acc[4][4] = {};

    const unsigned short* Abase = A + (size_t)bm * 128 * K;
    const unsigned short* Bbase = Bt + (size_t)bn * 128 * K;
    const int soff = tid * 16;

    auto STAGE = [&](int b, int kt){
        char* Ab = (char*)(sh + b*16384);
        char* Bb = (char*)(sh + b*16384 + 8192);
        #pragma unroll
        for (int s = 0; s < 4; ++s){
            const int off = s*4096 + soff;
            const int row = off >> 7, colb = off & 127;
            gload_lds16((const char*)(Abase + (size_t)row*K + kt) + colb, Ab + off);
        }
        #pragma unroll
        for (int s = 0; s < 4; ++s){
            const int off = s*4096 + soff;
            const int row = off >> 7, colb = off & 127;
            gload_lds16((const char*)(Bbase + (size_t)row*K + kt) + colb, Bb + off);
        }
    };
    auto COMPUTE = [&](int b){
        const unsigned short* Ab = sh + b*16384;
        const unsigned short* Bb = sh + b*16384 + 8192;
        #pragma unroll
        for (int ks = 0; ks < 2; ++ks){
            const int k0 = ks*32 + ((lane>>4)<<3);
            bf16x8 af[4], bfr[4];
            #pragma unroll
            for (int i=0;i<4;i++) af[i]  = *(const bf16x8*)&Ab[(wm + i*16 + (lane&15))*64 + k0];
            #pragma unroll
            for (int j=0;j<4;j++) bfr[j] = *(const bf16x8*)&Bb[(wn + j*16 + (lane&15))*64 + k0];
            #pragma unroll
            for (int i=0;i<4;i++)
                #pragma unroll
                for (int j=0;j<4;j++)
                    acc[i][j] = __builtin_amdgcn_mfma_f32_16x16x32_bf16(af[i], bfr[j], acc[i][j], 0, 0, 0);
        }
    };

    STAGE(0, 0);
    __syncthreads();
    const int nk = K >> 6;
    int cur = 0;
    for (int i = 0; i < nk; ++i){
        if (i + 1 < nk) STAGE(cur ^ 1, (i + 1) << 6);
        COMPUTE(cur);
        __syncthreads();
        cur ^= 1;
    }

    const int r0 = ((lane>>4)<<2);
    const int cc = lane & 15;
    unsigned short* Ct = sh;
    float bcol[4];
    #pragma unroll
    for (int j=0;j<4;j++) bcol[j] = bias[bn*128 + wn + j*16 + cc];
    #pragma unroll
    for (int i=0;i<4;i++)
        #pragma unroll
        for (int r=0;r<4;r++){
            const int rl = wm + i*16 + r0 + r;
            #pragma unroll
            for (int j=0;j<4;j++)
                Ct[rl*128 + wn + j*16 + cc] = f2bf(acc[i][j][r] + bcol[j]);
        }
    __syncthreads();
    const int orow = tid >> 4;
    const int ocol = (tid & 15) * 8;
    #pragma unroll
    for (int p = 0; p < 8; ++p){
        const int row = p*16 + orow;
        *(u16x8*)(&out[(size_t)(bm*128 + row)*N + bn*128 + ocol]) = *(u16x8*)&Ct[row*128 + ocol];
    }
}

// =============== 256x256 GEMM 2-phase dbuf BK=64 (ffn1) ===================
__global__ void __launch_bounds__(512, 2)
gemm256sq(const unsigned short* __restrict__ A, const unsigned short* __restrict__ Bt,
          const float* __restrict__ bias, unsigned short* __restrict__ out,
          int NB, int N, int K)
{
    __shared__ __align__(16) char sh[131072];
    const int nwg = gridDim.x;
    const int wg  = xcd_swizzle(blockIdx.x, nwg);
    const int bn  = wg % NB;
    const int bm  = wg / NB;
    const int m0  = bm * 256;
    const int n0  = bn * 256;

    const int tid = threadIdx.x, lane = tid & 63, wave = tid >> 6;
    const int wr = wave >> 2;
    const int wc = wave & 3;

    const int srow = wave*16 + (lane >> 3);
    const int scol = ((lane & 7) ^ (lane >> 3)) * 8;
    const unsigned short* aptr[2][2];
    const unsigned short* bptr[2][2];
    #pragma unroll
    for (int u = 0; u < 2; ++u)
        #pragma unroll
        for (int l = 0; l < 2; ++l){
            aptr[u][l] = A  + (size_t)(m0 + u*128 + srow + l*8) * K + scol;
            bptr[u][l] = Bt + (size_t)(n0 + u*128 + srow + l*8) * K + scol;
        }
    const int sdst = wave*2048 + lane*16;

    int ch[2];
    #pragma unroll
    for (int ks = 0; ks < 2; ++ks)
        ch[ks] = ((((ks<<2) + (lane>>4)) ^ (lane & 7)) << 4);
    const int arow = wr*128 + (lane & 15);
    const int brow = wc*64  + (lane & 15);

    f32x4 acc[8][4] = {};

    auto STAGE = [&](int buf, int kt){
        #pragma unroll
        for (int u = 0; u < 2; ++u)
            #pragma unroll
            for (int l = 0; l < 2; ++l)
                gload_lds16(aptr[u][l] + kt, sh + buf*32768 + u*16384 + l*1024 + sdst);
        #pragma unroll
        for (int u = 0; u < 2; ++u)
            #pragma unroll
            for (int l = 0; l < 2; ++l)
                gload_lds16(bptr[u][l] + kt, sh + 65536 + buf*32768 + u*16384 + l*1024 + sdst);
    };
    auto COMPUTE = [&](int buf){
        bf16x8 bfr[4][2];
        #pragma unroll
        for (int nf = 0; nf < 4; ++nf)
            #pragma unroll
            for (int ks = 0; ks < 2; ++ks)
                bfr[nf][ks] = *(const bf16x8*)(sh + 65536 + buf*32768 + (brow + nf*16)*128 + ch[ks]);
        #pragma unroll
        for (int mf = 0; mf < 8; ++mf){
            bf16x8 af[2];
            #pragma unroll
            for (int ks = 0; ks < 2; ++ks)
                af[ks] = *(const bf16x8*)(sh + buf*32768 + (arow + mf*16)*128 + ch[ks]);
            #pragma unroll
            for (int nf = 0; nf < 4; ++nf)
                #pragma unroll
                for (int ks = 0; ks < 2; ++ks)
                    acc[mf][nf] = __builtin_amdgcn_mfma_f32_16x16x32_bf16(af[ks], bfr[nf][ks], acc[mf][nf], 0,0,0);
        }
    };

    STAGE(0, 0);
    __syncthreads();
    const int nk = K >> 6;
    int cur = 0;
    for (int i = 0; i < nk; ++i){
        if (i + 1 < nk) STAGE(cur ^ 1, (i + 1) << 6);
        COMPUTE(cur);
        __syncthreads();
        cur ^= 1;
    }

    unsigned short* Ct = (unsigned short*)sh;
    const int r4 = (lane >> 4) * 4;
    const int cc = lane & 15;
    #pragma unroll
    for (int nf = 0; nf < 4; ++nf){
        const int col = wc*64 + nf*16 + cc;
        const float bv = bias[n0 + col];
        #pragma unroll
        for (int mf = 0; mf < 8; ++mf)
            #pragma unroll
            for (int r = 0; r < 4; ++r){
                const int row = wr*128 + mf*16 + r4 + r;
                Ct[row*256 + col] = f2bf(geluf(acc[mf][nf][r] + bv));
            }
    }
    __syncthreads();
    #pragma unroll
    for (int p = 0; p < 16; ++p){
        const int uidx = p*512 + tid;
        const int row = uidx >> 5;
        const int cu  = uidx & 31;
        *(u16x8*)(out + (size_t)(m0 + row)*N + n0 + cu*8) = *(const u16x8*)(Ct + row*256 + cu*8);
    }
}

// =================== 256x128 2-phase GEMM (attn/ffn2/MoE) =================
#define G_GELU_BF16 0
#define G_BF16_RESID 1
#define G_GATED_BF16 2

template<int EPI, int MOE, int INDIRECT>
__global__ void __launch_bounds__(512, 2)
gemm256(const unsigned short* __restrict__ A, const unsigned short* __restrict__ BtG,
        const float* __restrict__ biasG, const unsigned short* __restrict__ resid,
        const int* __restrict__ tok, const int* __restrict__ offs,
        int wstride, int bstride, const float* __restrict__ gslot,
        unsigned short* __restrict__ out, int NB, int N, int K)
{
    __shared__ __align__(16) char sh[147456];
    const int nwg = gridDim.x;
    const int wg  = xcd_swizzle(blockIdx.x, nwg);
    const int bn  = wg % NB;
    const int bm  = wg / NB;
    const int m0  = bm * 256;

    const unsigned short* Bt = BtG;
    const float* bias = biasG;
    if (MOE){
        if (m0 >= offs[8]) return;
        int e = 0;
        #pragma unroll 1
        while (offs[e+1] <= m0) ++e;
        Bt   += (size_t)e * wstride;
        bias += (size_t)e * bstride;
    }

    const int tid = threadIdx.x, lane = tid & 63, wave = tid >> 6;
    const int wm = (wave >> 1) * 64;
    const int wn = (wave & 1) * 64;

    const int srow = wave*16 + (lane >> 3);
    const int scol = ((lane & 7) ^ (lane >> 3)) * 8;
    const unsigned short* aptr[2][2];
    #pragma unroll
    for (int u = 0; u < 2; ++u)
        #pragma unroll
        for (int l = 0; l < 2; ++l){
            const int r = u*128 + srow + l*8;
            const int gr = INDIRECT ? tok[m0 + r] : (m0 + r);
            aptr[u][l] = A + (size_t)gr * K + scol;
        }
    const unsigned short* bptr[2];
    #pragma unroll
    for (int l = 0; l < 2; ++l)
        bptr[l] = Bt + (size_t)(bn*128 + srow + l*8) * K + scol;
    const int sdst = wave*2048 + lane*16;

    int aoff[2], boff[2];
    #pragma unroll
    for (int ks = 0; ks < 2; ++ks){
        const int ch = (((ks<<2) + (lane>>4)) ^ (lane & 7)) << 4;
        aoff[ks] = (wm + (lane & 15))*128 + ch;
        boff[ks] = (wn + (lane & 15))*128 + ch;
    }

    f32x4 acc[4][4] = {};

    auto STAGE = [&](int buf, int kt){
        #pragma unroll
        for (int u = 0; u < 2; ++u)
            #pragma unroll
            for (int l = 0; l < 2; ++l)
                gload_lds16(aptr[u][l] + kt, sh + buf*32768 + u*16384 + l*1024 + sdst);
        #pragma unroll
        for (int l = 0; l < 2; ++l)
            gload_lds16(bptr[l] + kt, sh + 98304 + buf*16384 + l*1024 + sdst);
    };
    auto COMPUTE = [&](int buf){
        bf16x8 bfr[4][2];
        #pragma unroll
        for (int nf = 0; nf < 4; ++nf)
            #pragma unroll
            for (int ks = 0; ks < 2; ++ks)
                bfr[nf][ks] = *(const bf16x8*)(sh + 98304 + buf*16384 + nf*2048 + boff[ks]);
        #pragma unroll
        for (int mf = 0; mf < 4; ++mf){
            bf16x8 af[2];
            #pragma unroll
            for (int ks = 0; ks < 2; ++ks)
                af[ks] = *(const bf16x8*)(sh + buf*32768 + mf*2048 + aoff[ks]);
            #pragma unroll
            for (int nf = 0; nf < 4; ++nf)
                #pragma unroll
                for (int ks = 0; ks < 2; ++ks)
                    acc[mf][nf] = __builtin_amdgcn_mfma_f32_16x16x32_bf16(af[ks], bfr[nf][ks], acc[mf][nf], 0,0,0);
        }
    };

    STAGE(0, 0);
    __syncthreads();
    const int nk = K >> 6;
    int cur = 0;
    for (int i = 0; i < nk; ++i){
        if (i + 1 < nk) STAGE(cur ^ 1, (i + 1) << 6);
        COMPUTE(cur);
        __syncthreads();
        cur ^= 1;
    }

    const int r4 = (lane >> 4) * 4;
    const int cc = lane & 15;
    if (EPI == G_BF16_RESID){
        float* ctf = (float*)sh;
        #pragma unroll
        for (int nf = 0; nf < 4; ++nf){
            const float bv = bias[bn*128 + wn + nf*16 + cc];
            #pragma unroll
            for (int mf = 0; mf < 4; ++mf)
                #pragma unroll
                for (int r = 0; r < 4; ++r){
                    const int row = wm + mf*16 + r4 + r;
                    ctf[row*128 + wn + nf*16 + cc] = acc[mf][nf][r] + bv;
                }
        }
        __syncthreads();
        #pragma unroll
        for (int p = 0; p < 8; ++p){
            const int uidx = p*512 + tid;
            const int row = uidx >> 4;
            const int cu  = uidx & 15;
            const size_t gidx = (size_t)(m0 + row)*N + bn*128 + cu*8;
            u16x8 hv = *(const u16x8*)(resid + gidx);
            u16x8 o;
            #pragma unroll
            for (int j = 0; j < 8; ++j)
                o[j] = f2bf(bf2f(hv[j]) + ctf[row*128 + cu*8 + j]);
            *(u16x8*)(out + gidx) = o;
        }
    } else {
        unsigned short* ct = (unsigned short*)sh;
        #pragma unroll
        for (int nf = 0; nf < 4; ++nf){
            const float bv = bias[bn*128 + wn + nf*16 + cc];
            #pragma unroll
            for (int mf = 0; mf < 4; ++mf)
                #pragma unroll
                for (int r = 0; r < 4; ++r){
                    const int row = wm + mf*16 + r4 + r;
                    float v = acc[mf][nf][r] + bv;
                    if (EPI == G_GELU_BF16) v = geluf(v);
                    else                    v *= gslot[m0 + row];
                    ct[row*128 + wn + nf*16 + cc] = f2bf(v);
                }
        }
        __syncthreads();
        #pragma unroll
        for (int p = 0; p < 8; ++p){
            const int uidx = p*512 + tid;
            const int row = uidx >> 4;
            const int cu  = uidx & 15;
            *(u16x8*)(out + (size_t)(m0 + row)*N + bn*128 + cu*8) =
                *(const u16x8*)(ct + row*128 + cu*8);
        }
    }
}

// ---------------- LayerNorm (bf16 in, bf16 out), one wave per row ---------
__global__ void ln_kernel(const unsigned short* __restrict__ x, const float* __restrict__ w,
                          const float* __restrict__ b, unsigned short* __restrict__ out)
{
    const int lane = threadIdx.x & 63;
    const int wave = threadIdx.x >> 6;
    const int row  = blockIdx.x * 4 + wave;
    u16x8 hv = *(const u16x8*)(x + (size_t)row * D_DIM + lane*8);
    float v[8];
    #pragma unroll
    for (int j = 0; j < 8; ++j) v[j] = bf2f(hv[j]);
    float s = 0.f, s2 = 0.f;
    #pragma unroll
    for (int j = 0; j < 8; ++j){ s += v[j]; s2 += v[j]*v[j]; }
    #pragma unroll
    for (int o = 32; o > 0; o >>= 1){ s += __shfl_xor(s, o); s2 += __shfl_xor(s2, o); }
    const float mean = s * (1.0f/512.0f);
    const float var  = s2 * (1.0f/512.0f) - mean*mean;
    const float inv  = 1.0f / sqrtf(var + 1e-5f);
    const int k = lane*8;
    u16x8 o;
    #pragma unroll
    for (int j = 0; j < 8; ++j) o[j] = f2bf((v[j]-mean)*inv*w[k+j] + b[k+j]);
    *(u16x8*)(out + (size_t)row*D_DIM + k) = o;
}

// ------- Router: softmax+eps-mix+top2 (bf16 z in, no global atomics) ------
__global__ void router_kernel(const unsigned short* __restrict__ z, const float* __restrict__ rw,
                              const float* __restrict__ rb,
                              int2* __restrict__ idx2, float2* __restrict__ wts2,
                              float* __restrict__ bsums)
{
    __shared__ float ps[4][8];
    const int lane = threadIdx.x & 63;
    const int wave = threadIdx.x >> 6;
    const int row  = blockIdx.x * 4 + wave;
    u16x8 hv = *(const u16x8*)(z + (size_t)row * D_DIM + lane*8);
    float acc[8] = {0,0,0,0,0,0,0,0};
    #pragma unroll
    for (int j = 0; j < 8; ++j){
        const float zv = bf2f(hv[j]);
        const float* wr = rw + (size_t)(lane*8 + j) * 8;
        f32x4 w0 = *(const f32x4*)wr;
        f32x4 w1 = *(const f32x4*)(wr + 4);
        acc[0] += zv*w0[0]; acc[1] += zv*w0[1]; acc[2] += zv*w0[2]; acc[3] += zv*w0[3];
        acc[4] += zv*w1[0]; acc[5] += zv*w1[1]; acc[6] += zv*w1[2]; acc[7] += zv*w1[3];
    }
    #pragma unroll
    for (int o = 32; o > 0; o >>= 1){
        #pragma unroll
        for (int e = 0; e < 8; ++e) acc[e] += __shfl_xor(acc[e], o);
    }
    if (lane == 0){
        float p[8]; float mx = -1e30f;
        #pragma unroll
        for (int e=0;e<8;e++){ p[e] = acc[e] + rb[e]; mx = fmaxf(mx, p[e]); }
        float se = 0.f;
        #pragma unroll
        for (int e=0;e<8;e++){ p[e] = expf(p[e]-mx); se += p[e]; }
        const float sc = 0.9f / se;
        #pragma unroll
        for (int e=0;e<8;e++) p[e] = p[e]*sc + 0.0125f;
        int i1 = 0;
        #pragma unroll
        for (int e=1;e<8;e++) if (p[e] > p[i1]) i1 = e;
        int i2 = (i1 == 0) ? 1 : 0;
        for (int e=i2+1;e<8;e++) if (e != i1 && p[e] > p[i2]) i2 = e;
        idx2[row] = make_int2(i1, i2);
        wts2[row] = make_float2(p[i1], p[i2]);
        #pragma unroll
        for (int e=0;e<8;e++) ps[wave][e] = p[e];
    }
    __syncthreads();
    if (threadIdx.x < 8){
        bsums[blockIdx.x*8 + threadIdx.x] =
            ps[0][threadIdx.x] + ps[1][threadIdx.x] + ps[2][threadIdx.x] + ps[3][threadIdx.x];
    }
}

// ------- histogram / scan / assign (block-local, no global atomics) -------
__global__ void hist_kernel(const int2* __restrict__ idx2, int* __restrict__ blockHist){
    __shared__ int hc[8];
    if (threadIdx.x < 8) hc[threadIdx.x] = 0;
    __syncthreads();
    const int t = blockIdx.x * 256 + threadIdx.x;
    const int2 ii = idx2[t];
    atomicAdd(&hc[ii.x], 1);
    atomicAdd(&hc[ii.y], 1);
    __syncthreads();
    if (threadIdx.x < 8) blockHist[blockIdx.x*8 + threadIdx.x] = hc[threadIdx.x];
}

__global__ void scan_kernel(const int* __restrict__ blockHist, int* __restrict__ offs,
                            int* __restrict__ baseArr){
    __shared__ int hist[NHBLK*8];
    __shared__ int cnt[8];
    __shared__ int start[8];
    const int t = threadIdx.x;
    hist[t] = blockHist[t];
    __syncthreads();
    if (t < 8){
        int c = 0;
        #pragma unroll 1
        for (int b = 0; b < NHBLK; ++b) c += hist[b*8 + t];
        cnt[t] = c;
    }
    __syncthreads();
    if (t == 0){
        int o = 0; offs[0] = 0;
        for (int e = 0; e < 8; ++e){ start[e] = o; o += (cnt[e]+255)&~255; offs[e+1] = o; }
    }
    __syncthreads();
    if (t < 8){
        int cur = start[t];
        #pragma unroll 1
        for (int b = 0; b < NHBLK; ++b){ baseArr[b*8 + t] = cur; cur += hist[b*8 + t]; }
    }
}

__global__ void assign_kernel(const int2* __restrict__ idx2, const float2* __restrict__ wts2,
                              const int* __restrict__ baseArr, int2* __restrict__ slot_map,
                              float* __restrict__ gslot, int* __restrict__ tok)
{
    __shared__ int cur[8];
    if (threadIdx.x < 8) cur[threadIdx.x] = 0;
    __syncthreads();
    const int t = blockIdx.x * 256 + threadIdx.x;
    const int2 ii = idx2[t];
    const float2 ww = wts2[t];
    const int r1 = atomicAdd(&cur[ii.x], 1);
    const int r2 = atomicAdd(&cur[ii.y], 1);
    const int s1 = baseArr[blockIdx.x*8 + ii.x] + r1;
    const int s2 = baseArr[blockIdx.x*8 + ii.y] + r2;
    slot_map[t] = make_int2(s1, s2);
    gslot[s1] = ww.x; gslot[s2] = ww.y;
    tok[s1] = t; tok[s2] = t;
}

// ---------------- aux loss ------------------------------------------------
__global__ void aux_kernel(const float* __restrict__ bsums, float* __restrict__ out_aux)
{
    __shared__ float part[256];
    const int t = threadIdx.x;
    const int e = t & 7, chunk = t >> 3;
    float s = 0.f;
    for (int blk = chunk*128; blk < chunk*128 + 128; ++blk) s += bsums[blk*8 + e];
    part[t] = s;
    __syncthreads();
    if (t < 8){
        float tot = 0.f;
        for (int c = 0; c < 32; ++c) tot += part[c*8 + t];
        part[t] = tot;
    }
    __syncthreads();
    if (t == 0){
        float aux = 0.f;
        for (int e2 = 0; e2 < 8; ++e2){
            float load = part[e2] * (1.0f/16384.0f);
            aux += load * logf(load * 8.0f + 1e-9f);
        }
        out_aux[0] = aux / 2.0794415416798357f;
    }
}

// -------- head: z = h + eo[s1] + eo[s2]; LN; dot --------------------------
__global__ void head_kernel(const unsigned short* __restrict__ h, const unsigned short* __restrict__ eog,
                            const int2* __restrict__ slot_map,
                            const float* __restrict__ w, const float* __restrict__ b,
                            const float* __restrict__ hw, const float* __restrict__ hb,
                            float* __restrict__ out)
{
    const int lane = threadIdx.x & 63;
    const int wave = threadIdx.x >> 6;
    const int row  = blockIdx.x * 4 + wave;
    const int2 sm = slot_map[row];
    u16x8 hv = *(const u16x8*)(h + (size_t)row * D_DIM + lane*8);
    u16x8 e1 = *(const u16x8*)(eog + (size_t)sm.x * D_DIM + lane*8);
    u16x8 e2 = *(const u16x8*)(eog + (size_t)sm.y * D_DIM + lane*8);
    float v[8];
    #pragma unroll
    for (int j=0;j<8;j++) v[j] = bf2f(hv[j]) + bf2f(e1[j]) + bf2f(e2[j]);
    float s = 0.f, s2 = 0.f;
    #pragma unroll
    for (int j=0;j<8;j++){ s += v[j]; s2 += v[j]*v[j]; }
    #pragma unroll
    for (int o = 32; o > 0; o >>= 1){ s += __shfl_xor(s, o); s2 += __shfl_xor(s2, o); }
    const float mean = s * (1.0f/512.0f);
    const float var  = s2 * (1.0f/512.0f) - mean*mean;
    const float inv  = 1.0f / sqrtf(var + 1e-5f);
    const int k = lane*8;
    float dot = 0.f;
    #pragma unroll
    for (int j=0;j<8;j++) dot += ((v[j]-mean)*inv*w[k+j] + b[k+j]) * hw[k+j];
    #pragma unroll
    for (int o = 32; o > 0; o >>= 1) dot += __shfl_xor(dot, o);
    if (lane == 0) out[row] = dot + hb[0];
}

// ===========================================================================
extern "C" void kernel_launch(void* const* d_in, const int* in_sizes, int n_in,
                              void* d_out, int out_size, void* d_ws, size_t ws_size,
                              hipStream_t stream)
{
    (void)in_sizes; (void)n_in; (void)out_size; (void)ws_size;
    const float* x         = (const float*)d_in[0];
    const float* embed_w   = (const float*)d_in[1];
    const float* embed_b   = (const float*)d_in[2];
    const float* ln1_w     = (const float*)d_in[3];
    const float* ln1_b     = (const float*)d_in[4];
    const float* inproj_w  = (const float*)d_in[5];
    const float* inproj_b  = (const float*)d_in[6];
    const float* outproj_w = (const float*)d_in[7];
    const float* outproj_b = (const float*)d_in[8];
    const float* ln2_w     = (const float*)d_in[9];
    const float* ln2_b     = (const float*)d_in[10];
    const float* ffn_w1    = (const float*)d_in[11];
    const float* ffn_b1    = (const float*)d_in[12];
    const float* ffn_w2    = (const float*)d_in[13];
    const float* ffn_b2    = (const float*)d_in[14];
    const float* router_w  = (const float*)d_in[15];
    const float* router_b  = (const float*)d_in[16];
    const float* exp_w1    = (const float*)d_in[17];
    const float* exp_b1    = (const float*)d_in[18];
    const float* exp_w2    = (const float*)d_in[19];
    const float* exp_b2    = (const float*)d_in[20];
    const float* head_ln_w = (const float*)d_in[21];
    const float* head_ln_b = (const float*)d_in[22];
    const float* head_w    = (const float*)d_in[23];
    const float* head_b    = (const float*)d_in[24];

    char* ws = (char*)d_ws;
    unsigned short* xbf   = (unsigned short*)(ws + 0);
    unsigned short* ebf   = (unsigned short*)(ws + 4194304);
    unsigned short* wobf  = (unsigned short*)(ws + 4325376);
    unsigned short* wvtbf = (unsigned short*)(ws + 5898240);
    unsigned short* wfold = (unsigned short*)(ws + 7471104);
    unsigned short* w1t   = (unsigned short*)(ws + 9043968);
    unsigned short* w2t   = (unsigned short*)(ws + 15335424);
    unsigned short* e1t   = (unsigned short*)(ws + 21626880);
    unsigned short* e2t   = (unsigned short*)(ws + 23724032);
    unsigned short* h     = (unsigned short*)(ws + 25821184);
    unsigned short* gbf   = (unsigned short*)(ws + 42598400);
    unsigned short* ubf   = (unsigned short*)(ws + 59375616);
    unsigned short* hmidg = ubf;
    unsigned short* eog   = (unsigned short*)(ws + 77201408);
    char* MISC = ws + 126484480;
    int*    offs     = (int*)(MISC + 0);
    float*  zbias    = (float*)(MISC + 256);
    float*  bfold    = (float*)(MISC + 2304);
    int2*   idx2     = (int2*)(MISC + 8448);
    float2* wts2     = (float2*)(MISC + 139520);
    int2*   slot_map = (int2*)(MISC + 270592);
    float*  gslot    = (float*)(MISC + 401664);
    int*    tok      = (int*)(MISC + 544768);
    float*  bsums    = (float*)(MISC + 684032);
    int*    blockHist= (int*)(MISC + 815104);
    int*    baseArr  = (int*)(MISC + 817152);
    float* out = (float*)d_out;

    zero_kernel<<<(MAXSLOT + 255)/256, 256, 0, stream>>>((int*)zbias, 512, tok, MAXSLOT);

    ConvArgs ca;
    ca.seg[0] = { x, xbf, B_TOK*IN_DIM/4 };
    ca.seg[1] = { outproj_w, wobf, DEPTH*D_DIM*D_DIM/4 };
    convert_kernel<<<1024, 256, 0, stream>>>(ca);

    TArgs ta;
    int tcur = 0, ti = 0;
    ta.seg[ti] = { embed_w, ebf, IN_DIM, D_DIM, tcur };
    tcur += (IN_DIM/32)*(D_DIM/32); ++ti;
    for (int l = 0; l < DEPTH; ++l){
        ta.seg[ti] = { ffn_w1 + (size_t)l*D_DIM*FF_DIM, w1t + (size_t)l*FF_DIM*D_DIM, D_DIM, FF_DIM, tcur };
        tcur += (D_DIM/32)*(FF_DIM/32); ++ti;
    }
    for (int l = 0; l < DEPTH; ++l){
        ta.seg[ti] = { ffn_w2 + (size_t)l*FF_DIM*D_DIM, w2t + (size_t)l*D_DIM*FF_DIM, FF_DIM, D_DIM, tcur };
        tcur += (FF_DIM/32)*(D_DIM/32); ++ti;
    }
    for (int e = 0; e < NEXP; ++e){
        ta.seg[ti] = { exp_w1 + (size_t)e*D_DIM*EH_DIM, e1t + (size_t)e*EH_DIM*D_DIM, D_DIM, EH_DIM, tcur };
        tcur += (D_DIM/32)*(EH_DIM/32); ++ti;
    }
    for (int e = 0; e < NEXP; ++e){
        ta.seg[ti] = { exp_w2 + (size_t)e*EH_DIM*D_DIM, e2t + (size_t)e*D_DIM*EH_DIM, EH_DIM, D_DIM, tcur };
        tcur += (EH_DIM/32)*(D_DIM/32); ++ti;
    }
    for (int l = 0; l < DEPTH; ++l){
        ta.seg[ti] = { inproj_w + (size_t)l*3*D_DIM*D_DIM + 2*D_DIM*D_DIM,
                       wvtbf + (size_t)l*D_DIM*D_DIM, D_DIM, D_DIM, tcur };
        tcur += (D_DIM/32)*(D_DIM/32); ++ti;
    }
    transpose_kernel<<<tcur, 256, 0, stream>>>(ta);

    foldb_kernel<<<DEPTH*D_DIM/4, 256, 0, stream>>>(outproj_w, outproj_b, inproj_b, bfold);

    gemm_bt<<<48, 256, 0, stream>>>(
        wobf, wvtbf, zbias, wfold, 4, D_DIM, D_DIM,
        16, (size_t)D_DIM*D_DIM, (size_t)D_DIM*D_DIM, (size_t)D_DIM*D_DIM);

    gemm_bt<<<(D_DIM/128)*(B_TOK/128), 256, 0, stream>>>(
        xbf, ebf, embed_b, h, D_DIM/128, D_DIM, IN_DIM,
        (D_DIM/128)*(B_TOK/128), 0, 0, 0);

    for (int l = 0; l < DEPTH; ++l){
        ln_kernel<<<B_TOK/4, 256, 0, stream>>>(h, ln1_w + l*D_DIM, ln1_b + l*D_DIM, gbf);
        gemm256<G_BF16_RESID,0,0><<<(B_TOK/256)*(D_DIM/128), 512, 0, stream>>>(
            gbf, wfold + (size_t)l*D_DIM*D_DIM, bfold + l*D_DIM, h,
            nullptr, nullptr, 0, 0, nullptr, h, D_DIM/128, D_DIM, D_DIM);
        ln_kernel<<<B_TOK/4, 256, 0, stream>>>(h, ln2_w + l*D_DIM, ln2_b + l*D_DIM, gbf);
        gemm256sq<<<(B_TOK/256)*(FF_DIM/256), 512, 0, stream>>>(
            gbf, w1t + (size_t)l*FF_DIM*D_DIM, ffn_b1 + l*FF_DIM, ubf, FF_DIM/256, FF_DIM, D_DIM);
        gemm256<G_BF16_RESID,0,0><<<(B_TOK/256)*(D_DIM/128), 512, 0, stream>>>(
            ubf, w2t + (size_t)l*D_DIM*FF_DIM, ffn_b2 + l*D_DIM, h,
            nullptr, nullptr, 0, 0, nullptr, h, D_DIM/128, D_DIM, FF_DIM);
    }

    router_kernel<<<B_TOK/4, 256, 0, stream>>>(h, router_w, router_b, idx2, wts2, bsums);
    aux_kernel<<<1, 256, 0, stream>>>(bsums, out + B_TOK);
    hist_kernel<<<NHBLK, 256, 0, stream>>>(idx2, blockHist);
    scan_kernel<<<1, 512, 0, stream>>>(blockHist, offs, baseArr);
    assign_kernel<<<B_TOK/256, 256, 0, stream>>>(idx2, wts2, baseArr, slot_map, gslot, tok);

    gemm256<G_GELU_BF16,1,1><<<MAXT256*(EH_DIM/128), 512, 0, stream>>>(
        h, e1t, exp_b1, nullptr, tok, offs, EH_DIM*D_DIM, EH_DIM, nullptr,
        hmidg, EH_DIM/128, EH_DIM, D_DIM);
    gemm256<G_GATED_BF16,1,0><<<MAXT256*(D_DIM/128), 512, 0, stream>>>(
        hmidg, e2t, exp_b2, nullptr, nullptr, offs, D_DIM*EH_DIM, D_DIM, gslot,
        eog, D_DIM/128, D_DIM, EH_DIM);

    head_kernel<<<B_TOK/4, 256, 0, stream>>>(h, eog, slot_map, head_ln_w, head_ln_b, head_w, head_b, out);
}